// Round 5
// baseline (582.824 us; speedup 1.0000x reference)
//
#include <hip/hip_runtime.h>

namespace {

// cos(2*pi*n/64); sin(2*pi*n/64) = COS64[(n+48)&63]
constexpr float COS64[64] = {
  1.00000000f,  0.99518473f,  0.98078528f,  0.95694034f,
  0.92387953f,  0.88192126f,  0.83146961f,  0.77301045f,
  0.70710678f,  0.63439328f,  0.55557023f,  0.47139674f,
  0.38268343f,  0.29028468f,  0.19509032f,  0.09801714f,
  0.00000000f, -0.09801714f, -0.19509032f, -0.29028468f,
 -0.38268343f, -0.47139674f, -0.55557023f, -0.63439328f,
 -0.70710678f, -0.77301045f, -0.83146961f, -0.88192126f,
 -0.92387953f, -0.95694034f, -0.98078528f, -0.99518473f,
 -1.00000000f, -0.99518473f, -0.98078528f, -0.95694034f,
 -0.92387953f, -0.88192126f, -0.83146961f, -0.77301045f,
 -0.70710678f, -0.63439328f, -0.55557023f, -0.47139674f,
 -0.38268343f, -0.29028468f, -0.19509032f, -0.09801714f,
 -0.00000000f,  0.09801714f,  0.19509032f,  0.29028468f,
  0.38268343f,  0.47139674f,  0.55557023f,  0.63439328f,
  0.70710678f,  0.77301045f,  0.83146961f,  0.88192126f,
  0.92387953f,  0.95694034f,  0.98078528f,  0.99518473f };

constexpr float TWOPI_64 = 0.09817477042468103f; // 2*pi/64
constexpr int MM = 144;   // 16 ky * 9 kz
constexpr int GD = 2304;  // 16 kx * 144

// ---------------------------------------------------------------------------
// KF: fused forward transform. Block = (chunk, bc); streams 16 h-slices.
// Per slice: z-DFT (quad shuffle reduce) -> As[kz][w] in LDS ->
// w-DFT (144 threads, 64-iter recurrence) -> Bs[m] in LDS ->
// h-DFT accumulate into registers (thread (kx,g) owns modes g*9..g*9+8).
// Writes partial S for its 16-h chunk.
// ---------------------------------------------------------------------------
__global__ __launch_bounds__(256, 4) void kf_fwd(const float* __restrict__ x,
                                                 float2* __restrict__ bufP) {
  constexpr int AS = 67;               // padded stride (conflict-free)
  __shared__ float2 As[9 * AS];        // A[kz][w]
  __shared__ float2 Bs[MM];            // B[ky*9+kz]
  const int tid = threadIdx.x;
  const int chunk = blockIdx.x, bc = blockIdx.y;
  const int h0 = chunk * 16;
  const int w = tid >> 2, q = tid & 3;

  // h-accumulation ownership: thread (kxo, g) owns modes m = g*9 + j
  const int kxo = tid >> 4, g = tid & 15;
  float accR[9], accI[9];
#pragma unroll
  for (int j = 0; j < 9; ++j) { accR[j] = 0.f; accI[j] = 0.f; }
  // running phase e^{-2pi i kxo h/64}, starting at h = h0
  const int n0 = (kxo * h0) & 63;
  float qR = COS64[n0], qI = -COS64[(n0 + 48) & 63];
  const float hc = COS64[kxo], hsn = COS64[(kxo + 48) & 63]; // cos, sin

  // w-DFT constants (thread-fixed): step e^{-2pi i ky/64}
  const int ky = tid / 9, kz = tid - ky * 9;   // valid for tid < MM
  const float wcs = COS64[ky & 63], wsn = COS64[((ky & 63) + 48) & 63];

  // x slice base; slice stride = 4096 floats = 1024 float4
  const float4* xpb = (const float4*)(x + ((size_t)(bc * 64 + h0) << 12));

  // prefetch slice 0
  float4 n0v = xpb[tid * 4 + 0];
  float4 n1v = xpb[tid * 4 + 1];
  float4 n2v = xpb[tid * 4 + 2];
  float4 n3v = xpb[tid * 4 + 3];

  for (int hh = 0; hh < 16; ++hh) {
    const float4 a0 = n0v, a1 = n1v, a2 = n2v, a3 = n3v;
    if (hh < 15) {                     // issue next-slice loads early (T14)
      const float4* xn = xpb + (size_t)(hh + 1) * 1024;
      n0v = xn[tid * 4 + 0];
      n1v = xn[tid * 4 + 1];
      n2v = xn[tid * 4 + 2];
      n3v = xn[tid * 4 + 3];
    }
    const float xv[16] = {a0.x, a0.y, a0.z, a0.w, a1.x, a1.y, a1.z, a1.w,
                          a2.x, a2.y, a2.z, a2.w, a3.x, a3.y, a3.z, a3.w};

    // --- z-DFT: sum_j xv[j] e^{-2pi i kzz j/64}, then quad reduce ---
    float ar[9], ai[9];
#pragma unroll
    for (int kzz = 0; kzz < 9; ++kzz) { ar[kzz] = 0.f; ai[kzz] = 0.f; }
#pragma unroll
    for (int j = 0; j < 16; ++j) {
      const float v = xv[j];
#pragma unroll
      for (int kzz = 0; kzz < 9; ++kzz) {
        const int n = (kzz * j) & 63;
        ar[kzz] = fmaf(v, COS64[n], ar[kzz]);
        ai[kzz] = fmaf(v, -COS64[(n + 48) & 63], ai[kzz]);
      }
    }
#pragma unroll
    for (int kzz = 0; kzz < 9; ++kzz) {
      const int m = (q * kzz) & 3;
      const float a = ar[kzz], b = ai[kzz];
      float r  = (m & 1) ? b : a;
      float i2 = (m & 1) ? a : b;
      r  = (m >= 2) ? -r : r;
      i2 = (m == 1 || m == 2) ? -i2 : i2;
      r  += __shfl_xor(r, 1);  r  += __shfl_xor(r, 2);
      i2 += __shfl_xor(i2, 1); i2 += __shfl_xor(i2, 2);
      if (q == 0) As[kzz * AS + w] = make_float2(r, i2);
    }
    __syncthreads();

    // --- w-DFT: B[ky][kz] = sum_w A[kz][w] e^{-2pi i ky w/64} ---
    if (tid < MM) {
      float px = 1.f, py = 0.f, br = 0.f, bi = 0.f;
      for (int ww = 0; ww < 64; ++ww) {
        const float2 a = As[kz * AS + ww];
        br = fmaf(a.x, px, fmaf(-a.y, py, br));
        bi = fmaf(a.x, py, fmaf( a.y, px, bi));
        const float nx = fmaf(px, wcs,  py * wsn);
        const float ny = fmaf(py, wcs, -px * wsn);
        px = nx; py = ny;
      }
      Bs[tid] = make_float2(br, bi);
    }
    __syncthreads();

    // --- h-DFT accumulate: S[kxo][m] += B[m] * e^{-2pi i kxo h/64} ---
#pragma unroll
    for (int j = 0; j < 9; ++j) {
      const float2 b = Bs[g * 9 + j];
      accR[j] = fmaf(b.x, qR, fmaf(-b.y, qI, accR[j]));
      accI[j] = fmaf(b.x, qI, fmaf( b.y, qR, accI[j]));
    }
    const float nR = fmaf(qR, hc, qI * hsn);
    const float nI = fmaf(qI, hc, -qR * hsn);
    qR = nR; qI = nI;
  }

  // store partial S
  float2* dst = bufP + ((size_t)(chunk * 256 + bc)) * GD + kxo * MM + g * 9;
#pragma unroll
  for (int j = 0; j < 9; ++j) dst[j] = make_float2(accR[j], accI[j]);
}

// ---------------------------------------------------------------------------
// K2b: sum the 4 chunk partials -> buf2
// ---------------------------------------------------------------------------
__global__ __launch_bounds__(256) void k2b_sum(const float2* __restrict__ bufP,
                                               float2* __restrict__ buf2) {
  const int bc = blockIdx.x, tid = threadIdx.x;
#pragma unroll
  for (int r = 0; r < 9; ++r) {
    const int idx = tid + 256 * r;
    float2 s = bufP[(size_t)bc * GD + idx];
#pragma unroll
    for (int c = 1; c < 4; ++c) {
      const float2 p = bufP[((size_t)(c * 256 + bc)) * GD + idx];
      s.x += p.x; s.y += p.y;
    }
    buf2[(size_t)bc * GD + idx] = s;
  }
}

// ---------------------------------------------------------------------------
// K3: gate MLP. pooled[b][c] = S_DC.re / 64^3. Writes g-1.
// ---------------------------------------------------------------------------
__global__ __launch_bounds__(256) void k3_gates(const float2* __restrict__ buf2,
    const float* __restrict__ w1, const float* __restrict__ b1,
    const float* __restrict__ w2, const float* __restrict__ b2,
    float* __restrict__ gm1) {
  __shared__ float pooled[64];
  __shared__ float hs[16];
  const int b = blockIdx.x, tid = threadIdx.x;
  if (tid < 64)
    pooled[tid] = buf2[(size_t)(b * 64 + tid) * GD].x * (1.f / 262144.f);
  __syncthreads();
  if (tid < 16) {
    float acc = b1[tid];
    for (int c = 0; c < 64; ++c) acc = fmaf(pooled[c], w1[c * 16 + tid], acc);
    hs[tid] = fmaxf(acc, 0.f);
  }
  __syncthreads();
#pragma unroll
  for (int r = 0; r < 9; ++r) {
    const int o = tid + r * 256;
    float acc = b2[o];
#pragma unroll
    for (int j = 0; j < 16; ++j) acc = fmaf(hs[j], w2[j * GD + o], acc);
    gm1[b * GD + o] = 1.f / (1.f + expf(-acc)) - 1.f;
  }
}

// ---------------------------------------------------------------------------
// K4b: inverse synthesis per slice, gate fused in phase 1; x prefetched at
//      block start so its HBM latency hides under phases 1-2.
//      out = x + delta/64^3 (plain stores: L2-merged, L3 write-back)
// ---------------------------------------------------------------------------
__global__ __launch_bounds__(256) void k4b_final(const float2* __restrict__ S,
                                                 const float* __restrict__ gm1,
                                                 const float* __restrict__ x,
                                                 float* __restrict__ out) {
  __shared__ float2 C1s[MM];
  __shared__ float2 C2s[9 * 65];       // C2[kz][w], padded
  const int tid = threadIdx.x, slice = blockIdx.x;
  const int bc = slice >> 6, h = slice & 63, b = bc >> 6;
  const int w = tid >> 2, q = tid & 3;

  // prefetch x early: 4 x float4 (64B per lane), consumed after phase 2
  const float4* xp = (const float4*)(x + ((size_t)slice << 12) + w * 64 + q * 16);
  float4 xv0 = xp[0];
  float4 xv1 = xp[1];
  float4 xv2 = xp[2];
  float4 xv3 = xp[3];

  // C1[m] = sum_kx (g-1)*S[bc][kx][m] e^{+2pi i kx h/64}
  if (tid < MM) {
    const float2* Sp = S + (size_t)bc * GD + tid;
    const float* Gp = gm1 + (size_t)b * GD + tid;
    float sn, cs;
    sincosf(TWOPI_64 * (float)h, &sn, &cs);   // step = e^{+2pi i h/64}
    float px = 1.f, py = 0.f, ar = 0.f, ai = 0.f;
#pragma unroll
    for (int kx = 0; kx < 16; ++kx) {
      const float2 sv = Sp[kx * MM];
      const float g = Gp[kx * MM];
      const float dR = sv.x * g, dI = sv.y * g;
      ar = fmaf(dR, px, fmaf(-dI, py, ar));
      ai = fmaf(dR, py, fmaf( dI, px, ai));
      const float nx = fmaf(px, cs, -py * sn);
      const float ny = fmaf(px, sn,  py * cs);
      px = nx; py = ny;
    }
    C1s[tid] = make_float2(ar, ai);
  }
  __syncthreads();

  // C2[kz][w] = sum_ky C1[ky*9+kz] e^{+2pi i ky w/64}; thread (w,q) does kz set
  {
    float sn, cs;
    sincosf(TWOPI_64 * (float)w, &sn, &cs);   // step = e^{+2pi i w/64}
    const int kz0 = q, kz1 = q + 4;           // q==0 also does kz=8
    float a0r = 0.f, a0i = 0.f, a1r = 0.f, a1i = 0.f, a2r = 0.f, a2i = 0.f;
    float px = 1.f, py = 0.f;
    for (int ky = 0; ky < 16; ++ky) {
      const float2 c0 = C1s[ky * 9 + kz0];
      const float2 c1 = C1s[ky * 9 + kz1];
      a0r = fmaf(c0.x, px, fmaf(-c0.y, py, a0r));
      a0i = fmaf(c0.x, py, fmaf( c0.y, px, a0i));
      a1r = fmaf(c1.x, px, fmaf(-c1.y, py, a1r));
      a1i = fmaf(c1.x, py, fmaf( c1.y, px, a1i));
      if (q == 0) {
        const float2 c2v = C1s[ky * 9 + 8];
        a2r = fmaf(c2v.x, px, fmaf(-c2v.y, py, a2r));
        a2i = fmaf(c2v.x, py, fmaf( c2v.y, px, a2i));
      }
      const float nx = fmaf(px, cs, -py * sn);
      const float ny = fmaf(px, sn,  py * cs);
      px = nx; py = ny;
    }
    C2s[kz0 * 65 + w] = make_float2(a0r, a0i);
    C2s[kz1 * 65 + w] = make_float2(a1r, a1i);
    if (q == 0) C2s[8 * 65 + w] = make_float2(a2r, a2i);
  }
  __syncthreads();

  // delta[w][d] = Re(C2[0]) + 2*sum_{kz>=1} Re(C2[kz] e^{+2pi i kz d/64});
  // d = 16q + j: e^{+2pi i kz d/64} = i^{kz q} * e^{+2pi i kz j/64}
  {
    float cr[9], ci[9];
#pragma unroll
    for (int kz = 0; kz < 9; ++kz) {
      const float2 v = C2s[kz * 65 + w];
      const int m = (kz * q) & 3;                 // multiply by i^m
      const float a = v.x, b2_ = v.y;
      float r  = (m & 1) ? b2_ : a;
      float i2 = (m & 1) ? a : b2_;
      r  = (m == 1 || m == 2) ? -r : r;
      i2 = (m >= 2) ? -i2 : i2;
      cr[kz] = r; ci[kz] = i2;
    }
    float acc[16];
#pragma unroll
    for (int j = 0; j < 16; ++j) acc[j] = cr[0];
#pragma unroll
    for (int kz = 1; kz < 9; ++kz) {
#pragma unroll
      for (int j = 0; j < 16; ++j) {
        const int n = (kz * j) & 63;
        acc[j] = fmaf(cr[kz],  2.f * COS64[n], acc[j]);
        acc[j] = fmaf(ci[kz], -2.f * COS64[(n + 48) & 63], acc[j]);
      }
    }
    float4* op = (float4*)(out + ((size_t)slice << 12) + w * 64 + q * 16);
    const float scale = 1.f / 262144.f;
    float4 o0 = xv0, o1 = xv1, o2 = xv2, o3 = xv3;
    o0.x += acc[0]  * scale; o0.y += acc[1]  * scale;
    o0.z += acc[2]  * scale; o0.w += acc[3]  * scale;
    o1.x += acc[4]  * scale; o1.y += acc[5]  * scale;
    o1.z += acc[6]  * scale; o1.w += acc[7]  * scale;
    o2.x += acc[8]  * scale; o2.y += acc[9]  * scale;
    o2.z += acc[10] * scale; o2.w += acc[11] * scale;
    o3.x += acc[12] * scale; o3.y += acc[13] * scale;
    o3.z += acc[14] * scale; o3.w += acc[15] * scale;
    op[0] = o0; op[1] = o1; op[2] = o2; op[3] = o3;
  }
}

} // namespace

extern "C" void kernel_launch(void* const* d_in, const int* in_sizes, int n_in,
                              void* d_out, int out_size, void* d_ws, size_t ws_size,
                              hipStream_t stream) {
  (void)in_sizes; (void)n_in; (void)out_size; (void)ws_size;
  const float* x  = (const float*)d_in[0];
  const float* w1 = (const float*)d_in[1];
  const float* b1 = (const float*)d_in[2];
  const float* w2 = (const float*)d_in[3];
  const float* b2 = (const float*)d_in[4];
  float* out = (float*)d_out;

  char* ws = (char*)d_ws;
  float2* bufP = (float2*)ws;                          // 4*256*2304*8 = 18,874,368 B
  float2* buf2 = (float2*)(ws + 18874368);             // 256*2304*8   =  4,718,592 B
  float*  gm1  = (float*)(ws + 18874368 + 4718592);    // 4*2304*4     =     36,864 B

  hipLaunchKernelGGL(kf_fwd,   dim3(4, 256),   dim3(256), 0, stream, x, bufP);
  hipLaunchKernelGGL(k2b_sum,  dim3(256),      dim3(256), 0, stream, bufP, buf2);
  hipLaunchKernelGGL(k3_gates, dim3(4),        dim3(256), 0, stream, buf2, w1, b1, w2, b2, gm1);
  hipLaunchKernelGGL(k4b_final,dim3(16384),    dim3(256), 0, stream, buf2, gm1, x, out);
}

// Round 6
// 306.643 us; speedup vs baseline: 1.9007x; 1.9007x over previous
//
#include <hip/hip_runtime.h>

namespace {

// cos(2*pi*n/64); sin(2*pi*n/64) = COS64[(n+48)&63]
constexpr float COS64[64] = {
  1.00000000f,  0.99518473f,  0.98078528f,  0.95694034f,
  0.92387953f,  0.88192126f,  0.83146961f,  0.77301045f,
  0.70710678f,  0.63439328f,  0.55557023f,  0.47139674f,
  0.38268343f,  0.29028468f,  0.19509032f,  0.09801714f,
  0.00000000f, -0.09801714f, -0.19509032f, -0.29028468f,
 -0.38268343f, -0.47139674f, -0.55557023f, -0.63439328f,
 -0.70710678f, -0.77301045f, -0.83146961f, -0.88192126f,
 -0.92387953f, -0.95694034f, -0.98078528f, -0.99518473f,
 -1.00000000f, -0.99518473f, -0.98078528f, -0.95694034f,
 -0.92387953f, -0.88192126f, -0.83146961f, -0.77301045f,
 -0.70710678f, -0.63439328f, -0.55557023f, -0.47139674f,
 -0.38268343f, -0.29028468f, -0.19509032f, -0.09801714f,
 -0.00000000f,  0.09801714f,  0.19509032f,  0.29028468f,
  0.38268343f,  0.47139674f,  0.55557023f,  0.63439328f,
  0.70710678f,  0.77301045f,  0.83146961f,  0.88192126f,
  0.92387953f,  0.95694034f,  0.98078528f,  0.99518473f };

// cos(2*pi*n/16); sin(2*pi*n/16) = C16[(n+12)&15]
constexpr float C16[16] = {
  1.00000000f,  0.92387953f,  0.70710678f,  0.38268343f,
  0.00000000f, -0.38268343f, -0.70710678f, -0.92387953f,
 -1.00000000f, -0.92387953f, -0.70710678f, -0.38268343f,
 -0.00000000f,  0.38268343f,  0.70710678f,  0.92387953f };

constexpr float TWOPI_64 = 0.09817477042468103f; // 2*pi/64
constexpr int MM = 144;   // 16 ky * 9 kz
constexpr int GD = 2304;  // 16 kx * 144
constexpr int ZW = 576;   // 9 kz * 64 w  (per-slice z-DFT output)

// ---------------------------------------------------------------------------
// K1: pure streaming z-DFT. x[slice][w][d] -> buf1[slice][kz*64 + w] complex.
// No LDS, no barrier: 4-lane shuffle reduce, q==0 lanes store.
// ---------------------------------------------------------------------------
__global__ __launch_bounds__(256) void k1_fwd(const float* __restrict__ x,
                                              float2* __restrict__ buf1) {
  const int tid = threadIdx.x;
  const int slice = blockIdx.x;        // bc*64 + h
  const int w = tid >> 2, q = tid & 3;

  const float4* xp = (const float4*)(x + ((size_t)slice << 12));
  float4 a0 = xp[tid * 4 + 0];
  float4 a1 = xp[tid * 4 + 1];
  float4 a2 = xp[tid * 4 + 2];
  float4 a3 = xp[tid * 4 + 3];
  float xv[16] = {a0.x, a0.y, a0.z, a0.w, a1.x, a1.y, a1.z, a1.w,
                  a2.x, a2.y, a2.z, a2.w, a3.x, a3.y, a3.z, a3.w};

  // partial z-DFT with compile-time twiddles: sum_j xv[j] e^{-2pi i kz j/64}
  float ar[9], ai[9];
#pragma unroll
  for (int kz = 0; kz < 9; ++kz) { ar[kz] = 0.f; ai[kz] = 0.f; }
#pragma unroll
  for (int j = 0; j < 16; ++j) {
    const float v = xv[j];
#pragma unroll
    for (int kz = 0; kz < 9; ++kz) {
      const int n = (kz * j) & 63;
      ar[kz] = fmaf(v, COS64[n], ar[kz]);
      ai[kz] = fmaf(v, -COS64[(n + 48) & 63], ai[kz]);
    }
  }
  // rotate by (-i)^{(q*kz)&3} (the e^{-2pi i kz 16q/64} factor), reduce over q
  float2* bp = buf1 + (size_t)slice * ZW;
#pragma unroll
  for (int kz = 0; kz < 9; ++kz) {
    const int m = (q * kz) & 3;
    const float a = ar[kz], b = ai[kz];
    float r  = (m & 1) ? b : a;
    float i2 = (m & 1) ? a : b;
    r  = (m >= 2) ? -r : r;
    i2 = (m == 1 || m == 2) ? -i2 : i2;
    r  += __shfl_xor(r, 1);  r  += __shfl_xor(r, 2);
    i2 += __shfl_xor(i2, 1); i2 += __shfl_xor(i2, 2);
    if (q == 0) bp[kz * 64 + w] = make_float2(r, i2);
  }
}

// ---------------------------------------------------------------------------
// K2: per (bc, kz): w-DFT (64->16 ky) then h-DFT (64->16 kx).
// grid (9, 256). LDS: As[h][w] XOR-swizzled on w; Bs[h][ky] stride 17.
// ---------------------------------------------------------------------------
__global__ __launch_bounds__(256) void k2_fwd(const float2* __restrict__ buf1,
                                              float2* __restrict__ buf2) {
  __shared__ float2 As[64 * 64];       // idx = h*64 + (w ^ (h&31))
  __shared__ float2 Bs[64 * 17];       // idx = h*17 + ky
  const int tid = threadIdx.x;
  const int kz = blockIdx.x, bc = blockIdx.y;

  // load: thread holds w = tid&63 fixed, h = (tid>>6)+4i
  {
    const int wl = tid & 63, hb = tid >> 6;
#pragma unroll
    for (int i = 0; i < 16; ++i) {
      const int h = hb + 4 * i;
      As[h * 64 + (wl ^ (h & 31))] =
          buf1[((size_t)bc * 64 + h) * ZW + kz * 64 + wl];
    }
  }
  __syncthreads();

  // w-DFT: thread (h = tid&63, kyg = tid>>6) computes ky = kyg+4j, j=0..3
  const int h = tid & 63, kyg = tid >> 6;
  float bR[4] = {0.f, 0.f, 0.f, 0.f}, bI[4] = {0.f, 0.f, 0.f, 0.f};
  {
    const float sc = COS64[kyg];              // step = e^{-2pi i kyg/64}
    const float ss = COS64[(kyg + 48) & 63];  // sin
    float pR = 1.f, pI = 0.f;
    const int hl = h & 31;
    const float2* Ah = As + h * 64;
    for (int w1 = 0; w1 < 4; ++w1) {
#pragma unroll
      for (int w0 = 0; w0 < 16; ++w0) {
        const int w = w1 * 16 + w0;
        const float2 a = Ah[w ^ hl];
        const float tR = a.x * pR - a.y * pI;
        const float tI = a.x * pI + a.y * pR;
        bR[0] += tR; bI[0] += tI;
#pragma unroll
        for (int j = 1; j < 4; ++j) {
          const int n = (j * w0) & 15;
          const float c = C16[n], s = C16[(n + 12) & 15];
          bR[j] = fmaf(tR, c, fmaf(tI, s, bR[j]));
          bI[j] = fmaf(tI, c, fmaf(-tR, s, bI[j]));
        }
        const float nR = fmaf(pR, sc, pI * ss);
        const float nI = fmaf(pI, sc, -pR * ss);
        pR = nR; pI = nI;
      }
    }
  }
#pragma unroll
  for (int j = 0; j < 4; ++j)
    Bs[h * 17 + kyg + 4 * j] = make_float2(bR[j], bI[j]);
  __syncthreads();

  // h-DFT: thread (kx = tid>>4, ky = tid&15)
  {
    const int kx = tid >> 4, ky = tid & 15;
    const float hc = COS64[kx];               // step = e^{-2pi i kx/64}
    const float hs = COS64[(kx + 48) & 63];
    float qR = 1.f, qI = 0.f, sR = 0.f, sI = 0.f;
    for (int h2 = 0; h2 < 64; ++h2) {
      const float2 b = Bs[h2 * 17 + ky];
      sR = fmaf(b.x, qR, fmaf(-b.y, qI, sR));
      sI = fmaf(b.x, qI, fmaf( b.y, qR, sI));
      const float nR = fmaf(qR, hc, qI * hs);
      const float nI = fmaf(qI, hc, -qR * hs);
      qR = nR; qI = nI;
    }
    buf2[(size_t)bc * GD + kx * MM + ky * 9 + kz] = make_float2(sR, sI);
  }
}

// ---------------------------------------------------------------------------
// K3: gate MLP. pooled[b][c] = S_DC.re / 64^3. Writes g-1.
// ---------------------------------------------------------------------------
__global__ __launch_bounds__(256) void k3_gates(const float2* __restrict__ buf2,
    const float* __restrict__ w1, const float* __restrict__ b1,
    const float* __restrict__ w2, const float* __restrict__ b2,
    float* __restrict__ gm1) {
  __shared__ float pooled[64];
  __shared__ float hs[16];
  const int b = blockIdx.x, tid = threadIdx.x;
  if (tid < 64)
    pooled[tid] = buf2[(size_t)(b * 64 + tid) * GD].x * (1.f / 262144.f);
  __syncthreads();
  if (tid < 16) {
    float acc = b1[tid];
    for (int c = 0; c < 64; ++c) acc = fmaf(pooled[c], w1[c * 16 + tid], acc);
    hs[tid] = fmaxf(acc, 0.f);
  }
  __syncthreads();
#pragma unroll
  for (int r = 0; r < 9; ++r) {
    const int o = tid + r * 256;
    float acc = b2[o];
#pragma unroll
    for (int j = 0; j < 16; ++j) acc = fmaf(hs[j], w2[j * GD + o], acc);
    gm1[b * GD + o] = 1.f / (1.f + expf(-acc)) - 1.f;
  }
}

// ---------------------------------------------------------------------------
// K4b: inverse synthesis, TWO slices (h0, h0+32) per block.
// Phase 1: one S/gm1 load + one twiddle chain feeds both slices via
//          e^{+2pi i kx(h+32)/64} = (-1)^kx e^{+2pi i kx h/64}.
// Phase 2: shared twiddle recurrence, two independent accumulation streams.
// Phase 3: per-slice synthesis; slice-1 x prefetch issued before slice-0
//          synthesis so its latency hides under ~330 VALU ops.
// ---------------------------------------------------------------------------
__global__ __launch_bounds__(256) void k4b_final(const float2* __restrict__ S,
                                                 const float* __restrict__ gm1,
                                                 const float* __restrict__ x,
                                                 float* __restrict__ out) {
  __shared__ float2 C1s[2][MM];
  __shared__ float2 C2s[2][9 * 65];    // C2[s][kz][w], padded
  const int tid = threadIdx.x;
  const int bc = blockIdx.x >> 5, h0 = blockIdx.x & 31;  // h1 = h0 + 32
  const int b = bc >> 6;
  const int w = tid >> 2, q = tid & 3;

  const size_t base0 = (((size_t)(bc * 64 + h0)) << 12) + w * 64 + q * 16;
  const size_t base1 = base0 + ((size_t)32 << 12);

  // prefetch x slice 0 early
  const float4* xp0 = (const float4*)(x + base0);
  float4 xa0 = xp0[0], xa1 = xp0[1], xa2 = xp0[2], xa3 = xp0[3];

  // --- phase 1: C1[s][m] = sum_kx (g-1)*S[bc][kx][m] e^{+2pi i kx h_s/64} ---
  if (tid < MM) {
    const float2* Sp = S + (size_t)bc * GD + tid;
    const float* Gp = gm1 + (size_t)b * GD + tid;
    float sn, cs;
    sincosf(TWOPI_64 * (float)h0, &sn, &cs);  // step = e^{+2pi i h0/64}
    float px = 1.f, py = 0.f;
    float a0r = 0.f, a0i = 0.f, a1r = 0.f, a1i = 0.f;
#pragma unroll
    for (int kx = 0; kx < 16; ++kx) {
      const float2 sv = Sp[kx * MM];
      const float g = Gp[kx * MM];
      const float dR = sv.x * g, dI = sv.y * g;
      const float tR = fmaf(dR, px, -dI * py);   // T = D * ph(kx)
      const float tI = fmaf(dR, py,  dI * px);
      a0r += tR; a0i += tI;
      if (kx & 1) { a1r -= tR; a1i -= tI; } else { a1r += tR; a1i += tI; }
      const float nx = fmaf(px, cs, -py * sn);
      const float ny = fmaf(px, sn,  py * cs);
      px = nx; py = ny;
    }
    C1s[0][tid] = make_float2(a0r, a0i);
    C1s[1][tid] = make_float2(a1r, a1i);
  }
  __syncthreads();

  // --- phase 2: C2[s][kz][w] = sum_ky C1[s][ky*9+kz] e^{+2pi i ky w/64} ---
  {
    float sn, cs;
    sincosf(TWOPI_64 * (float)w, &sn, &cs);   // step = e^{+2pi i w/64}
    const int kz0 = q, kz1 = q + 4;           // q==0 also does kz=8
    float A0r[2] = {0.f, 0.f}, A0i[2] = {0.f, 0.f};
    float A1r[2] = {0.f, 0.f}, A1i[2] = {0.f, 0.f};
    float A2r[2] = {0.f, 0.f}, A2i[2] = {0.f, 0.f};
    float px = 1.f, py = 0.f;
    for (int ky = 0; ky < 16; ++ky) {
#pragma unroll
      for (int s = 0; s < 2; ++s) {
        const float2 c0 = C1s[s][ky * 9 + kz0];
        const float2 c1 = C1s[s][ky * 9 + kz1];
        A0r[s] = fmaf(c0.x, px, fmaf(-c0.y, py, A0r[s]));
        A0i[s] = fmaf(c0.x, py, fmaf( c0.y, px, A0i[s]));
        A1r[s] = fmaf(c1.x, px, fmaf(-c1.y, py, A1r[s]));
        A1i[s] = fmaf(c1.x, py, fmaf( c1.y, px, A1i[s]));
        if (q == 0) {
          const float2 c2v = C1s[s][ky * 9 + 8];
          A2r[s] = fmaf(c2v.x, px, fmaf(-c2v.y, py, A2r[s]));
          A2i[s] = fmaf(c2v.x, py, fmaf( c2v.y, px, A2i[s]));
        }
      }
      const float nx = fmaf(px, cs, -py * sn);
      const float ny = fmaf(px, sn,  py * cs);
      px = nx; py = ny;
    }
#pragma unroll
    for (int s = 0; s < 2; ++s) {
      C2s[s][kz0 * 65 + w] = make_float2(A0r[s], A0i[s]);
      C2s[s][kz1 * 65 + w] = make_float2(A1r[s], A1i[s]);
      if (q == 0) C2s[s][8 * 65 + w] = make_float2(A2r[s], A2i[s]);
    }
  }
  __syncthreads();

  // prefetch x slice 1 now; latency hides under slice-0 synthesis
  const float4* xp1 = (const float4*)(x + base1);
  float4 xb0 = xp1[0], xb1 = xp1[1], xb2 = xp1[2], xb3 = xp1[3];

  // --- phase 3: per-slice inverse z synthesis + out = x + delta/64^3 ---
#pragma unroll
  for (int s = 0; s < 2; ++s) {
    float cr[9], ci[9];
#pragma unroll
    for (int kz = 0; kz < 9; ++kz) {
      const float2 v = C2s[s][kz * 65 + w];
      const int m = (kz * q) & 3;                 // multiply by i^m
      const float a = v.x, b2_ = v.y;
      float r  = (m & 1) ? b2_ : a;
      float i2 = (m & 1) ? a : b2_;
      r  = (m == 1 || m == 2) ? -r : r;
      i2 = (m >= 2) ? -i2 : i2;
      cr[kz] = r; ci[kz] = i2;
    }
    float acc[16];
#pragma unroll
    for (int j = 0; j < 16; ++j) acc[j] = cr[0];
#pragma unroll
    for (int kz = 1; kz < 9; ++kz) {
#pragma unroll
      for (int j = 0; j < 16; ++j) {
        const int n = (kz * j) & 63;
        acc[j] = fmaf(cr[kz],  2.f * COS64[n], acc[j]);
        acc[j] = fmaf(ci[kz], -2.f * COS64[(n + 48) & 63], acc[j]);
      }
    }
    float4* op = (float4*)(out + (s == 0 ? base0 : base1));
    const float scale = 1.f / 262144.f;
    float4 o0 = (s == 0) ? xa0 : xb0;
    float4 o1 = (s == 0) ? xa1 : xb1;
    float4 o2 = (s == 0) ? xa2 : xb2;
    float4 o3 = (s == 0) ? xa3 : xb3;
    o0.x += acc[0]  * scale; o0.y += acc[1]  * scale;
    o0.z += acc[2]  * scale; o0.w += acc[3]  * scale;
    o1.x += acc[4]  * scale; o1.y += acc[5]  * scale;
    o1.z += acc[6]  * scale; o1.w += acc[7]  * scale;
    o2.x += acc[8]  * scale; o2.y += acc[9]  * scale;
    o2.z += acc[10] * scale; o2.w += acc[11] * scale;
    o3.x += acc[12] * scale; o3.y += acc[13] * scale;
    o3.z += acc[14] * scale; o3.w += acc[15] * scale;
    op[0] = o0; op[1] = o1; op[2] = o2; op[3] = o3;
  }
}

} // namespace

extern "C" void kernel_launch(void* const* d_in, const int* in_sizes, int n_in,
                              void* d_out, int out_size, void* d_ws, size_t ws_size,
                              hipStream_t stream) {
  (void)in_sizes; (void)n_in; (void)out_size; (void)ws_size;
  const float* x  = (const float*)d_in[0];
  const float* w1 = (const float*)d_in[1];
  const float* b1 = (const float*)d_in[2];
  const float* w2 = (const float*)d_in[3];
  const float* b2 = (const float*)d_in[4];
  float* out = (float*)d_out;

  char* ws = (char*)d_ws;
  float2* buf1 = (float2*)ws;                          // 16384*576*8 = 75,497,472 B
  float2* buf2 = (float2*)(ws + 75497472);             // 256*2304*8  =  4,718,592 B
  float*  gm1  = (float*)(ws + 75497472 + 4718592);    // 4*2304*4    =     36,864 B

  hipLaunchKernelGGL(k1_fwd,   dim3(16384),    dim3(256), 0, stream, x, buf1);
  hipLaunchKernelGGL(k2_fwd,   dim3(9, 256),   dim3(256), 0, stream, buf1, buf2);
  hipLaunchKernelGGL(k3_gates, dim3(4),        dim3(256), 0, stream, buf2, w1, b1, w2, b2, gm1);
  hipLaunchKernelGGL(k4b_final,dim3(8192),     dim3(256), 0, stream, buf2, gm1, x, out);
}

// Round 7
// 279.939 us; speedup vs baseline: 2.0820x; 1.0954x over previous
//
#include <hip/hip_runtime.h>

namespace {

// cos(2*pi*n/64); sin(2*pi*n/64) = COS64[(n+48)&63]
constexpr float COS64[64] = {
  1.00000000f,  0.99518473f,  0.98078528f,  0.95694034f,
  0.92387953f,  0.88192126f,  0.83146961f,  0.77301045f,
  0.70710678f,  0.63439328f,  0.55557023f,  0.47139674f,
  0.38268343f,  0.29028468f,  0.19509032f,  0.09801714f,
  0.00000000f, -0.09801714f, -0.19509032f, -0.29028468f,
 -0.38268343f, -0.47139674f, -0.55557023f, -0.63439328f,
 -0.70710678f, -0.77301045f, -0.83146961f, -0.88192126f,
 -0.92387953f, -0.95694034f, -0.98078528f, -0.99518473f,
 -1.00000000f, -0.99518473f, -0.98078528f, -0.95694034f,
 -0.92387953f, -0.88192126f, -0.83146961f, -0.77301045f,
 -0.70710678f, -0.63439328f, -0.55557023f, -0.47139674f,
 -0.38268343f, -0.29028468f, -0.19509032f, -0.09801714f,
 -0.00000000f,  0.09801714f,  0.19509032f,  0.29028468f,
  0.38268343f,  0.47139674f,  0.55557023f,  0.63439328f,
  0.70710678f,  0.77301045f,  0.83146961f,  0.88192126f,
  0.92387953f,  0.95694034f,  0.98078528f,  0.99518473f };

// cos(2*pi*n/16); sin(2*pi*n/16) = C16[(n+12)&15]
constexpr float C16[16] = {
  1.00000000f,  0.92387953f,  0.70710678f,  0.38268343f,
  0.00000000f, -0.38268343f, -0.70710678f, -0.92387953f,
 -1.00000000f, -0.92387953f, -0.70710678f, -0.38268343f,
 -0.00000000f,  0.38268343f,  0.70710678f,  0.92387953f };

constexpr float TWOPI_64 = 0.09817477042468103f; // 2*pi/64
constexpr int MM = 144;   // 16 ky * 9 kz
constexpr int GD = 2304;  // 16 kx * 144
constexpr int ZW = 576;   // 9 kz * 64 w  (per-slice z-DFT output)

// ---------------------------------------------------------------------------
// K1: pure streaming z-DFT. x[slice][w][d] -> buf1[slice][kz*64 + w] complex.
// No LDS, no barrier: 4-lane shuffle reduce, q==0 lanes store.
// ---------------------------------------------------------------------------
__global__ __launch_bounds__(256) void k1_fwd(const float* __restrict__ x,
                                              float2* __restrict__ buf1) {
  const int tid = threadIdx.x;
  const int slice = blockIdx.x;        // bc*64 + h
  const int w = tid >> 2, q = tid & 3;

  const float4* xp = (const float4*)(x + ((size_t)slice << 12));
  float4 a0 = xp[tid * 4 + 0];
  float4 a1 = xp[tid * 4 + 1];
  float4 a2 = xp[tid * 4 + 2];
  float4 a3 = xp[tid * 4 + 3];
  float xv[16] = {a0.x, a0.y, a0.z, a0.w, a1.x, a1.y, a1.z, a1.w,
                  a2.x, a2.y, a2.z, a2.w, a3.x, a3.y, a3.z, a3.w};

  // partial z-DFT with compile-time twiddles: sum_j xv[j] e^{-2pi i kz j/64}
  float ar[9], ai[9];
#pragma unroll
  for (int kz = 0; kz < 9; ++kz) { ar[kz] = 0.f; ai[kz] = 0.f; }
#pragma unroll
  for (int j = 0; j < 16; ++j) {
    const float v = xv[j];
#pragma unroll
    for (int kz = 0; kz < 9; ++kz) {
      const int n = (kz * j) & 63;
      ar[kz] = fmaf(v, COS64[n], ar[kz]);
      ai[kz] = fmaf(v, -COS64[(n + 48) & 63], ai[kz]);
    }
  }
  // rotate by (-i)^{(q*kz)&3} (the e^{-2pi i kz 16q/64} factor), reduce over q
  float2* bp = buf1 + (size_t)slice * ZW;
#pragma unroll
  for (int kz = 0; kz < 9; ++kz) {
    const int m = (q * kz) & 3;
    const float a = ar[kz], b = ai[kz];
    float r  = (m & 1) ? b : a;
    float i2 = (m & 1) ? a : b;
    r  = (m >= 2) ? -r : r;
    i2 = (m == 1 || m == 2) ? -i2 : i2;
    r  += __shfl_xor(r, 1);  r  += __shfl_xor(r, 2);
    i2 += __shfl_xor(i2, 1); i2 += __shfl_xor(i2, 2);
    if (q == 0) bp[kz * 64 + w] = make_float2(r, i2);
  }
}

// ---------------------------------------------------------------------------
// K2: per (bc, kz): w-DFT (64->16 ky) then h-DFT (64->16 kx).
// grid (9, 256). LDS: As[h][w] XOR-swizzled on w; Bs[h][ky] stride 17.
// ---------------------------------------------------------------------------
__global__ __launch_bounds__(256) void k2_fwd(const float2* __restrict__ buf1,
                                              float2* __restrict__ buf2) {
  __shared__ float2 As[64 * 64];       // idx = h*64 + (w ^ (h&31))
  __shared__ float2 Bs[64 * 17];       // idx = h*17 + ky
  const int tid = threadIdx.x;
  const int kz = blockIdx.x, bc = blockIdx.y;

  // load: thread holds w = tid&63 fixed, h = (tid>>6)+4i
  {
    const int wl = tid & 63, hb = tid >> 6;
#pragma unroll
    for (int i = 0; i < 16; ++i) {
      const int h = hb + 4 * i;
      As[h * 64 + (wl ^ (h & 31))] =
          buf1[((size_t)bc * 64 + h) * ZW + kz * 64 + wl];
    }
  }
  __syncthreads();

  // w-DFT: thread (h = tid&63, kyg = tid>>6) computes ky = kyg+4j, j=0..3
  const int h = tid & 63, kyg = tid >> 6;
  float bR[4] = {0.f, 0.f, 0.f, 0.f}, bI[4] = {0.f, 0.f, 0.f, 0.f};
  {
    const float sc = COS64[kyg];              // step = e^{-2pi i kyg/64}
    const float ss = COS64[(kyg + 48) & 63];  // sin
    float pR = 1.f, pI = 0.f;
    const int hl = h & 31;
    const float2* Ah = As + h * 64;
    for (int w1 = 0; w1 < 4; ++w1) {
#pragma unroll
      for (int w0 = 0; w0 < 16; ++w0) {
        const int w = w1 * 16 + w0;
        const float2 a = Ah[w ^ hl];
        const float tR = a.x * pR - a.y * pI;
        const float tI = a.x * pI + a.y * pR;
        bR[0] += tR; bI[0] += tI;
#pragma unroll
        for (int j = 1; j < 4; ++j) {
          const int n = (j * w0) & 15;
          const float c = C16[n], s = C16[(n + 12) & 15];
          bR[j] = fmaf(tR, c, fmaf(tI, s, bR[j]));
          bI[j] = fmaf(tI, c, fmaf(-tR, s, bI[j]));
        }
        const float nR = fmaf(pR, sc, pI * ss);
        const float nI = fmaf(pI, sc, -pR * ss);
        pR = nR; pI = nI;
      }
    }
  }
#pragma unroll
  for (int j = 0; j < 4; ++j)
    Bs[h * 17 + kyg + 4 * j] = make_float2(bR[j], bI[j]);
  __syncthreads();

  // h-DFT: thread (kx = tid>>4, ky = tid&15)
  {
    const int kx = tid >> 4, ky = tid & 15;
    const float hc = COS64[kx];               // step = e^{-2pi i kx/64}
    const float hs = COS64[(kx + 48) & 63];
    float qR = 1.f, qI = 0.f, sR = 0.f, sI = 0.f;
    for (int h2 = 0; h2 < 64; ++h2) {
      const float2 b = Bs[h2 * 17 + ky];
      sR = fmaf(b.x, qR, fmaf(-b.y, qI, sR));
      sI = fmaf(b.x, qI, fmaf( b.y, qR, sI));
      const float nR = fmaf(qR, hc, qI * hs);
      const float nI = fmaf(qI, hc, -qR * hs);
      qR = nR; qI = nI;
    }
    buf2[(size_t)bc * GD + kx * MM + ky * 9 + kz] = make_float2(sR, sI);
  }
}

// ---------------------------------------------------------------------------
// K3: gate MLP. pooled[b][c] = S_DC.re / 64^3. Writes g-1.
// ---------------------------------------------------------------------------
__global__ __launch_bounds__(256) void k3_gates(const float2* __restrict__ buf2,
    const float* __restrict__ w1, const float* __restrict__ b1,
    const float* __restrict__ w2, const float* __restrict__ b2,
    float* __restrict__ gm1) {
  __shared__ float pooled[64];
  __shared__ float hs[16];
  const int b = blockIdx.x, tid = threadIdx.x;
  if (tid < 64)
    pooled[tid] = buf2[(size_t)(b * 64 + tid) * GD].x * (1.f / 262144.f);
  __syncthreads();
  if (tid < 16) {
    float acc = b1[tid];
    for (int c = 0; c < 64; ++c) acc = fmaf(pooled[c], w1[c * 16 + tid], acc);
    hs[tid] = fmaxf(acc, 0.f);
  }
  __syncthreads();
#pragma unroll
  for (int r = 0; r < 9; ++r) {
    const int o = tid + r * 256;
    float acc = b2[o];
#pragma unroll
    for (int j = 0; j < 16; ++j) acc = fmaf(hs[j], w2[j * GD + o], acc);
    gm1[b * GD + o] = 1.f / (1.f + expf(-acc)) - 1.f;
  }
}

// ---------------------------------------------------------------------------
// K4b: inverse synthesis per slice (1 slice/block, VGPR-lean), with
//  - phase 1: batched D loads (dv[16] array -> one waitcnt) and two 8-step
//    chains merged by F = e^{+2pi i 8h/64}
//  - phase 2: two 8-step chains merged by G = e^{+2pi i 8w/64}
//  - x prefetched at block start; plain stores (L2-merge/L3 write-back)
// ---------------------------------------------------------------------------
__global__ __launch_bounds__(256) void k4b_final(const float2* __restrict__ S,
                                                 const float* __restrict__ gm1,
                                                 const float* __restrict__ x,
                                                 float* __restrict__ out) {
  __shared__ float2 C1s[MM];
  __shared__ float2 C2s[9 * 65];       // C2[kz][w], padded
  const int tid = threadIdx.x, slice = blockIdx.x;
  const int bc = slice >> 6, h = slice & 63, b = bc >> 6;
  const int w = tid >> 2, q = tid & 3;

  // prefetch x early: 4 x float4 (64B per lane), consumed in phase 3
  const float4* xp = (const float4*)(x + ((size_t)slice << 12) + w * 64 + q * 16);
  float4 xv0 = xp[0];
  float4 xv1 = xp[1];
  float4 xv2 = xp[2];
  float4 xv3 = xp[3];

  // --- phase 1: C1[m] = sum_kx (g-1)*S[bc][kx][m] e^{+2pi i kx h/64} ---
  if (tid < MM) {
    const float2* Sp = S + (size_t)bc * GD + tid;
    const float* Gp = gm1 + (size_t)b * GD + tid;
    float2 dv[16];
#pragma unroll
    for (int kx = 0; kx < 16; ++kx) {
      const float2 sv = Sp[kx * MM];
      const float g = Gp[kx * MM];
      dv[kx] = make_float2(sv.x * g, sv.y * g);
    }
    float sn, cs;
    sincosf(TWOPI_64 * (float)h, &sn, &cs);   // step = e^{+2pi i h/64}
    float px = 1.f, py = 0.f;
    float aR = 0.f, aI = 0.f, bR = 0.f, bI = 0.f;   // two independent chains
#pragma unroll
    for (int kx = 0; kx < 8; ++kx) {
      const float2 d0 = dv[kx], d1 = dv[kx + 8];
      aR = fmaf(d0.x, px, fmaf(-d0.y, py, aR));
      aI = fmaf(d0.x, py, fmaf( d0.y, px, aI));
      bR = fmaf(d1.x, px, fmaf(-d1.y, py, bR));
      bI = fmaf(d1.x, py, fmaf( d1.y, px, bI));
      const float nx = fmaf(px, cs, -py * sn);
      const float ny = fmaf(px, sn,  py * cs);
      px = nx; py = ny;
    }
    // merge: C1 = a + F*b, F = e^{+2pi i 8h/64}
    const int n8 = (8 * h) & 63;
    const float FR = COS64[n8], FI = COS64[(n8 + 48) & 63];
    const float ar = aR + FR * bR - FI * bI;
    const float ai = aI + FR * bI + FI * bR;
    C1s[tid] = make_float2(ar, ai);
  }
  __syncthreads();

  // --- phase 2: C2[kz][w] = sum_ky C1[ky*9+kz] e^{+2pi i ky w/64} ---
  {
    float sn, cs;
    sincosf(TWOPI_64 * (float)w, &sn, &cs);   // step = e^{+2pi i w/64}
    const int kz0 = q, kz1 = q + 4;           // q==0 also does kz=8
    // two chains per kz: ky 0..7 and 8..15
    float a0r[2] = {0.f, 0.f}, a0i[2] = {0.f, 0.f};
    float a1r[2] = {0.f, 0.f}, a1i[2] = {0.f, 0.f};
    float a2r[2] = {0.f, 0.f}, a2i[2] = {0.f, 0.f};
    float px = 1.f, py = 0.f;
#pragma unroll
    for (int ky = 0; ky < 8; ++ky) {
#pragma unroll
      for (int c = 0; c < 2; ++c) {
        const float2 c0 = C1s[(ky + 8 * c) * 9 + kz0];
        const float2 c1 = C1s[(ky + 8 * c) * 9 + kz1];
        a0r[c] = fmaf(c0.x, px, fmaf(-c0.y, py, a0r[c]));
        a0i[c] = fmaf(c0.x, py, fmaf( c0.y, px, a0i[c]));
        a1r[c] = fmaf(c1.x, px, fmaf(-c1.y, py, a1r[c]));
        a1i[c] = fmaf(c1.x, py, fmaf( c1.y, px, a1i[c]));
        if (q == 0) {
          const float2 c2v = C1s[(ky + 8 * c) * 9 + 8];
          a2r[c] = fmaf(c2v.x, px, fmaf(-c2v.y, py, a2r[c]));
          a2i[c] = fmaf(c2v.x, py, fmaf( c2v.y, px, a2i[c]));
        }
      }
      const float nx = fmaf(px, cs, -py * sn);
      const float ny = fmaf(px, sn,  py * cs);
      px = nx; py = ny;
    }
    // merge with G = e^{+2pi i 8w/64}
    const int n8 = (8 * w) & 63;
    const float GR = COS64[n8], GI = COS64[(n8 + 48) & 63];
    C2s[kz0 * 65 + w] = make_float2(a0r[0] + GR * a0r[1] - GI * a0i[1],
                                    a0i[0] + GR * a0i[1] + GI * a0r[1]);
    C2s[kz1 * 65 + w] = make_float2(a1r[0] + GR * a1r[1] - GI * a1i[1],
                                    a1i[0] + GR * a1i[1] + GI * a1r[1]);
    if (q == 0)
      C2s[8 * 65 + w] = make_float2(a2r[0] + GR * a2r[1] - GI * a2i[1],
                                    a2i[0] + GR * a2i[1] + GI * a2r[1]);
  }
  __syncthreads();

  // --- phase 3: delta[w][d] = Re(C2[0]) + 2*sum_{kz>=1} Re(C2[kz] e^{+2pi i kz d/64})
  // d = 16q + j: e^{+2pi i kz d/64} = i^{kz q} * e^{+2pi i kz j/64}
  {
    float cr[9], ci[9];
#pragma unroll
    for (int kz = 0; kz < 9; ++kz) {
      const float2 v = C2s[kz * 65 + w];
      const int m = (kz * q) & 3;                 // multiply by i^m
      const float a = v.x, b2_ = v.y;
      float r  = (m & 1) ? b2_ : a;
      float i2 = (m & 1) ? a : b2_;
      r  = (m == 1 || m == 2) ? -r : r;
      i2 = (m >= 2) ? -i2 : i2;
      cr[kz] = r; ci[kz] = i2;
    }
    float acc[16];
#pragma unroll
    for (int j = 0; j < 16; ++j) acc[j] = cr[0];
#pragma unroll
    for (int kz = 1; kz < 9; ++kz) {
#pragma unroll
      for (int j = 0; j < 16; ++j) {
        const int n = (kz * j) & 63;
        acc[j] = fmaf(cr[kz],  2.f * COS64[n], acc[j]);
        acc[j] = fmaf(ci[kz], -2.f * COS64[(n + 48) & 63], acc[j]);
      }
    }
    float4* op = (float4*)(out + ((size_t)slice << 12) + w * 64 + q * 16);
    const float scale = 1.f / 262144.f;
    float4 o0 = xv0, o1 = xv1, o2 = xv2, o3 = xv3;
    o0.x += acc[0]  * scale; o0.y += acc[1]  * scale;
    o0.z += acc[2]  * scale; o0.w += acc[3]  * scale;
    o1.x += acc[4]  * scale; o1.y += acc[5]  * scale;
    o1.z += acc[6]  * scale; o1.w += acc[7]  * scale;
    o2.x += acc[8]  * scale; o2.y += acc[9]  * scale;
    o2.z += acc[10] * scale; o2.w += acc[11] * scale;
    o3.x += acc[12] * scale; o3.y += acc[13] * scale;
    o3.z += acc[14] * scale; o3.w += acc[15] * scale;
    op[0] = o0; op[1] = o1; op[2] = o2; op[3] = o3;
  }
}

} // namespace

extern "C" void kernel_launch(void* const* d_in, const int* in_sizes, int n_in,
                              void* d_out, int out_size, void* d_ws, size_t ws_size,
                              hipStream_t stream) {
  (void)in_sizes; (void)n_in; (void)out_size; (void)ws_size;
  const float* x  = (const float*)d_in[0];
  const float* w1 = (const float*)d_in[1];
  const float* b1 = (const float*)d_in[2];
  const float* w2 = (const float*)d_in[3];
  const float* b2 = (const float*)d_in[4];
  float* out = (float*)d_out;

  char* ws = (char*)d_ws;
  float2* buf1 = (float2*)ws;                          // 16384*576*8 = 75,497,472 B
  float2* buf2 = (float2*)(ws + 75497472);             // 256*2304*8  =  4,718,592 B
  float*  gm1  = (float*)(ws + 75497472 + 4718592);    // 4*2304*4    =     36,864 B

  hipLaunchKernelGGL(k1_fwd,   dim3(16384),    dim3(256), 0, stream, x, buf1);
  hipLaunchKernelGGL(k2_fwd,   dim3(9, 256),   dim3(256), 0, stream, buf1, buf2);
  hipLaunchKernelGGL(k3_gates, dim3(4),        dim3(256), 0, stream, buf2, w1, b1, w2, b2, gm1);
  hipLaunchKernelGGL(k4b_final,dim3(16384),    dim3(256), 0, stream, buf2, gm1, x, out);
}

// Round 8
// 256.103 us; speedup vs baseline: 2.2757x; 1.0931x over previous
//
#include <hip/hip_runtime.h>

namespace {

// cos(2*pi*n/64); sin(2*pi*n/64) = COS64[(n+48)&63]
constexpr float COS64[64] = {
  1.00000000f,  0.99518473f,  0.98078528f,  0.95694034f,
  0.92387953f,  0.88192126f,  0.83146961f,  0.77301045f,
  0.70710678f,  0.63439328f,  0.55557023f,  0.47139674f,
  0.38268343f,  0.29028468f,  0.19509032f,  0.09801714f,
  0.00000000f, -0.09801714f, -0.19509032f, -0.29028468f,
 -0.38268343f, -0.47139674f, -0.55557023f, -0.63439328f,
 -0.70710678f, -0.77301045f, -0.83146961f, -0.88192126f,
 -0.92387953f, -0.95694034f, -0.98078528f, -0.99518473f,
 -1.00000000f, -0.99518473f, -0.98078528f, -0.95694034f,
 -0.92387953f, -0.88192126f, -0.83146961f, -0.77301045f,
 -0.70710678f, -0.63439328f, -0.55557023f, -0.47139674f,
 -0.38268343f, -0.29028468f, -0.19509032f, -0.09801714f,
 -0.00000000f,  0.09801714f,  0.19509032f,  0.29028468f,
  0.38268343f,  0.47139674f,  0.55557023f,  0.63439328f,
  0.70710678f,  0.77301045f,  0.83146961f,  0.88192126f,
  0.92387953f,  0.95694034f,  0.98078528f,  0.99518473f };

// cos(2*pi*n/16); sin(2*pi*n/16) = C16[(n+12)&15]
constexpr float C16[16] = {
  1.00000000f,  0.92387953f,  0.70710678f,  0.38268343f,
  0.00000000f, -0.38268343f, -0.70710678f, -0.92387953f,
 -1.00000000f, -0.92387953f, -0.70710678f, -0.38268343f,
 -0.00000000f,  0.38268343f,  0.70710678f,  0.92387953f };

constexpr float TWOPI_64 = 0.09817477042468103f; // 2*pi/64
constexpr int MM = 144;   // 16 ky * 9 kz
constexpr int GD = 2304;  // 16 kx * 144
constexpr int ZW = 576;   // 9 kz * 64 w  (per-slice z-DFT output)

// ---------------------------------------------------------------------------
// K1: streaming z-DFT with wave-contiguous x loads.
// Loads xp[tid+256k] (1KB/inst), stages through padded LDS [64][68]
// (uniform 8 lanes per 16B bank-slot = conflict-free b128), then the
// verified z-DFT (compile-time twiddles + quad shuffle reduce).
// ---------------------------------------------------------------------------
__global__ __launch_bounds__(256) void k1_fwd(const float* __restrict__ x,
                                              float2* __restrict__ buf1) {
  __shared__ float xs[64 * 68];        // [w][68], pad 4
  const int tid = threadIdx.x;
  const int slice = blockIdx.x;        // bc*64 + h
  const int w = tid >> 2, q = tid & 3;

  const float4* xp = (const float4*)(x + ((size_t)slice << 12));
  const float4 a0 = xp[tid];
  const float4 a1 = xp[tid + 256];
  const float4 a2 = xp[tid + 512];
  const float4 a3 = xp[tid + 768];
  {
    // float4 index i = tid + 256k -> w' = (tid>>4)+16k, d' = (tid&15)*4
    const int s0 = tid & 15, hi = tid >> 4;
    *(float4*)&xs[(hi +  0) * 68 + s0 * 4] = a0;
    *(float4*)&xs[(hi + 16) * 68 + s0 * 4] = a1;
    *(float4*)&xs[(hi + 32) * 68 + s0 * 4] = a2;
    *(float4*)&xs[(hi + 48) * 68 + s0 * 4] = a3;
  }
  __syncthreads();

  float xv[16];
  {
    const float4 b0 = *(const float4*)&xs[w * 68 + q * 16 + 0];
    const float4 b1 = *(const float4*)&xs[w * 68 + q * 16 + 4];
    const float4 b2 = *(const float4*)&xs[w * 68 + q * 16 + 8];
    const float4 b3 = *(const float4*)&xs[w * 68 + q * 16 + 12];
    xv[0]=b0.x; xv[1]=b0.y; xv[2]=b0.z; xv[3]=b0.w;
    xv[4]=b1.x; xv[5]=b1.y; xv[6]=b1.z; xv[7]=b1.w;
    xv[8]=b2.x; xv[9]=b2.y; xv[10]=b2.z; xv[11]=b2.w;
    xv[12]=b3.x; xv[13]=b3.y; xv[14]=b3.z; xv[15]=b3.w;
  }

  // partial z-DFT with compile-time twiddles: sum_j xv[j] e^{-2pi i kz j/64}
  float ar[9], ai[9];
#pragma unroll
  for (int kz = 0; kz < 9; ++kz) { ar[kz] = 0.f; ai[kz] = 0.f; }
#pragma unroll
  for (int j = 0; j < 16; ++j) {
    const float v = xv[j];
#pragma unroll
    for (int kz = 0; kz < 9; ++kz) {
      const int n = (kz * j) & 63;
      ar[kz] = fmaf(v, COS64[n], ar[kz]);
      ai[kz] = fmaf(v, -COS64[(n + 48) & 63], ai[kz]);
    }
  }
  // rotate by (-i)^{(q*kz)&3} (the e^{-2pi i kz 16q/64} factor), reduce over q
  float2* bp = buf1 + (size_t)slice * ZW;
#pragma unroll
  for (int kz = 0; kz < 9; ++kz) {
    const int m = (q * kz) & 3;
    const float a = ar[kz], b = ai[kz];
    float r  = (m & 1) ? b : a;
    float i2 = (m & 1) ? a : b;
    r  = (m >= 2) ? -r : r;
    i2 = (m == 1 || m == 2) ? -i2 : i2;
    r  += __shfl_xor(r, 1);  r  += __shfl_xor(r, 2);
    i2 += __shfl_xor(i2, 1); i2 += __shfl_xor(i2, 2);
    if (q == 0) bp[kz * 64 + w] = make_float2(r, i2);
  }
}

// ---------------------------------------------------------------------------
// K2: per (bc, kz): w-DFT (64->16 ky) then h-DFT (64->16 kx).
// grid (9, 256). LDS: As[h][w] XOR-swizzled on w; Bs[h][ky] stride 17.
// ---------------------------------------------------------------------------
__global__ __launch_bounds__(256) void k2_fwd(const float2* __restrict__ buf1,
                                              float2* __restrict__ buf2) {
  __shared__ float2 As[64 * 64];       // idx = h*64 + (w ^ (h&31))
  __shared__ float2 Bs[64 * 17];       // idx = h*17 + ky
  const int tid = threadIdx.x;
  const int kz = blockIdx.x, bc = blockIdx.y;

  // load: thread holds w = tid&63 fixed, h = (tid>>6)+4i
  {
    const int wl = tid & 63, hb = tid >> 6;
#pragma unroll
    for (int i = 0; i < 16; ++i) {
      const int h = hb + 4 * i;
      As[h * 64 + (wl ^ (h & 31))] =
          buf1[((size_t)bc * 64 + h) * ZW + kz * 64 + wl];
    }
  }
  __syncthreads();

  // w-DFT: thread (h = tid&63, kyg = tid>>6) computes ky = kyg+4j, j=0..3
  const int h = tid & 63, kyg = tid >> 6;
  float bR[4] = {0.f, 0.f, 0.f, 0.f}, bI[4] = {0.f, 0.f, 0.f, 0.f};
  {
    const float sc = COS64[kyg];              // step = e^{-2pi i kyg/64}
    const float ss = COS64[(kyg + 48) & 63];  // sin
    float pR = 1.f, pI = 0.f;
    const int hl = h & 31;
    const float2* Ah = As + h * 64;
    for (int w1 = 0; w1 < 4; ++w1) {
#pragma unroll
      for (int w0 = 0; w0 < 16; ++w0) {
        const int w = w1 * 16 + w0;
        const float2 a = Ah[w ^ hl];
        const float tR = a.x * pR - a.y * pI;
        const float tI = a.x * pI + a.y * pR;
        bR[0] += tR; bI[0] += tI;
#pragma unroll
        for (int j = 1; j < 4; ++j) {
          const int n = (j * w0) & 15;
          const float c = C16[n], s = C16[(n + 12) & 15];
          bR[j] = fmaf(tR, c, fmaf(tI, s, bR[j]));
          bI[j] = fmaf(tI, c, fmaf(-tR, s, bI[j]));
        }
        const float nR = fmaf(pR, sc, pI * ss);
        const float nI = fmaf(pI, sc, -pR * ss);
        pR = nR; pI = nI;
      }
    }
  }
#pragma unroll
  for (int j = 0; j < 4; ++j)
    Bs[h * 17 + kyg + 4 * j] = make_float2(bR[j], bI[j]);
  __syncthreads();

  // h-DFT: thread (kx = tid>>4, ky = tid&15)
  {
    const int kx = tid >> 4, ky = tid & 15;
    const float hc = COS64[kx];               // step = e^{-2pi i kx/64}
    const float hs = COS64[(kx + 48) & 63];
    float qR = 1.f, qI = 0.f, sR = 0.f, sI = 0.f;
    for (int h2 = 0; h2 < 64; ++h2) {
      const float2 b = Bs[h2 * 17 + ky];
      sR = fmaf(b.x, qR, fmaf(-b.y, qI, sR));
      sI = fmaf(b.x, qI, fmaf( b.y, qR, sI));
      const float nR = fmaf(qR, hc, qI * hs);
      const float nI = fmaf(qI, hc, -qR * hs);
      qR = nR; qI = nI;
    }
    buf2[(size_t)bc * GD + kx * MM + ky * 9 + kz] = make_float2(sR, sI);
  }
}

// ---------------------------------------------------------------------------
// K3: gate MLP. pooled[b][c] = S_DC.re / 64^3. Writes g-1.
// ---------------------------------------------------------------------------
__global__ __launch_bounds__(256) void k3_gates(const float2* __restrict__ buf2,
    const float* __restrict__ w1, const float* __restrict__ b1,
    const float* __restrict__ w2, const float* __restrict__ b2,
    float* __restrict__ gm1) {
  __shared__ float pooled[64];
  __shared__ float hs[16];
  const int b = blockIdx.x, tid = threadIdx.x;
  if (tid < 64)
    pooled[tid] = buf2[(size_t)(b * 64 + tid) * GD].x * (1.f / 262144.f);
  __syncthreads();
  if (tid < 16) {
    float acc = b1[tid];
    for (int c = 0; c < 64; ++c) acc = fmaf(pooled[c], w1[c * 16 + tid], acc);
    hs[tid] = fmaxf(acc, 0.f);
  }
  __syncthreads();
#pragma unroll
  for (int r = 0; r < 9; ++r) {
    const int o = tid + r * 256;
    float acc = b2[o];
#pragma unroll
    for (int j = 0; j < 16; ++j) acc = fmaf(hs[j], w2[j * GD + o], acc);
    gm1[b * GD + o] = 1.f / (1.f + expf(-acc)) - 1.f;
  }
}

// ---------------------------------------------------------------------------
// K4b: inverse synthesis per slice. Phases 1-2 as verified (R4). Phase 3
// writes scaled delta into padded LDS [64][68]; after a barrier each lane
// reads its linear chunk, adds x (loaded wave-contiguously at block start),
// and stores wave-contiguous 1KB per inst.
// ---------------------------------------------------------------------------
__global__ __launch_bounds__(256) void k4b_final(const float2* __restrict__ S,
                                                 const float* __restrict__ gm1,
                                                 const float* __restrict__ x,
                                                 float* __restrict__ out) {
  __shared__ float2 C1s[MM];
  __shared__ float2 C2s[9 * 65];       // C2[kz][w], padded
  __shared__ float deltaS[64 * 68];    // [w][68], pad 4
  const int tid = threadIdx.x, slice = blockIdx.x;
  const int bc = slice >> 6, h = slice & 63, b = bc >> 6;
  const int w = tid >> 2, q = tid & 3;

  // prefetch x wave-contiguously: xp[tid+256k] = 1KB/inst
  const float4* xp = (const float4*)(x + ((size_t)slice << 12));
  const float4 xv0 = xp[tid];
  const float4 xv1 = xp[tid + 256];
  const float4 xv2 = xp[tid + 512];
  const float4 xv3 = xp[tid + 768];

  // --- phase 1: C1[m] = sum_kx (g-1)*S[bc][kx][m] e^{+2pi i kx h/64} ---
  if (tid < MM) {
    const float2* Sp = S + (size_t)bc * GD + tid;
    const float* Gp = gm1 + (size_t)b * GD + tid;
    float sn, cs;
    sincosf(TWOPI_64 * (float)h, &sn, &cs);   // step = e^{+2pi i h/64}
    float px = 1.f, py = 0.f, ar = 0.f, ai = 0.f;
#pragma unroll
    for (int kx = 0; kx < 16; ++kx) {
      const float2 sv = Sp[kx * MM];
      const float g = Gp[kx * MM];
      const float dR = sv.x * g, dI = sv.y * g;
      ar = fmaf(dR, px, fmaf(-dI, py, ar));
      ai = fmaf(dR, py, fmaf( dI, px, ai));
      const float nx = fmaf(px, cs, -py * sn);
      const float ny = fmaf(px, sn,  py * cs);
      px = nx; py = ny;
    }
    C1s[tid] = make_float2(ar, ai);
  }
  __syncthreads();

  // --- phase 2: C2[kz][w] = sum_ky C1[ky*9+kz] e^{+2pi i ky w/64} ---
  {
    float sn, cs;
    sincosf(TWOPI_64 * (float)w, &sn, &cs);   // step = e^{+2pi i w/64}
    const int kz0 = q, kz1 = q + 4;           // q==0 also does kz=8
    float a0r = 0.f, a0i = 0.f, a1r = 0.f, a1i = 0.f, a2r = 0.f, a2i = 0.f;
    float px = 1.f, py = 0.f;
    for (int ky = 0; ky < 16; ++ky) {
      const float2 c0 = C1s[ky * 9 + kz0];
      const float2 c1 = C1s[ky * 9 + kz1];
      a0r = fmaf(c0.x, px, fmaf(-c0.y, py, a0r));
      a0i = fmaf(c0.x, py, fmaf( c0.y, px, a0i));
      a1r = fmaf(c1.x, px, fmaf(-c1.y, py, a1r));
      a1i = fmaf(c1.x, py, fmaf( c1.y, px, a1i));
      if (q == 0) {
        const float2 c2v = C1s[ky * 9 + 8];
        a2r = fmaf(c2v.x, px, fmaf(-c2v.y, py, a2r));
        a2i = fmaf(c2v.x, py, fmaf( c2v.y, px, a2i));
      }
      const float nx = fmaf(px, cs, -py * sn);
      const float ny = fmaf(px, sn,  py * cs);
      px = nx; py = ny;
    }
    C2s[kz0 * 65 + w] = make_float2(a0r, a0i);
    C2s[kz1 * 65 + w] = make_float2(a1r, a1i);
    if (q == 0) C2s[8 * 65 + w] = make_float2(a2r, a2i);
  }
  __syncthreads();

  // --- phase 3: delta[w][d] = Re(C2[0]) + 2*sum_{kz>=1} Re(C2[kz] e^{+2pi i kz d/64})
  // d = 16q + j: e^{+2pi i kz d/64} = i^{kz q} * e^{+2pi i kz j/64}
  {
    float cr[9], ci[9];
#pragma unroll
    for (int kz = 0; kz < 9; ++kz) {
      const float2 v = C2s[kz * 65 + w];
      const int m = (kz * q) & 3;                 // multiply by i^m
      const float a = v.x, b2_ = v.y;
      float r  = (m & 1) ? b2_ : a;
      float i2 = (m & 1) ? a : b2_;
      r  = (m == 1 || m == 2) ? -r : r;
      i2 = (m >= 2) ? -i2 : i2;
      cr[kz] = r; ci[kz] = i2;
    }
    float acc[16];
#pragma unroll
    for (int j = 0; j < 16; ++j) acc[j] = cr[0];
#pragma unroll
    for (int kz = 1; kz < 9; ++kz) {
#pragma unroll
      for (int j = 0; j < 16; ++j) {
        const int n = (kz * j) & 63;
        acc[j] = fmaf(cr[kz],  2.f * COS64[n], acc[j]);
        acc[j] = fmaf(ci[kz], -2.f * COS64[(n + 48) & 63], acc[j]);
      }
    }
    const float scale = 1.f / 262144.f;
    float4 d0, d1, d2, d3;
    d0.x = acc[0]  * scale; d0.y = acc[1]  * scale;
    d0.z = acc[2]  * scale; d0.w = acc[3]  * scale;
    d1.x = acc[4]  * scale; d1.y = acc[5]  * scale;
    d1.z = acc[6]  * scale; d1.w = acc[7]  * scale;
    d2.x = acc[8]  * scale; d2.y = acc[9]  * scale;
    d2.z = acc[10] * scale; d2.w = acc[11] * scale;
    d3.x = acc[12] * scale; d3.y = acc[13] * scale;
    d3.z = acc[14] * scale; d3.w = acc[15] * scale;
    *(float4*)&deltaS[w * 68 + q * 16 + 0]  = d0;
    *(float4*)&deltaS[w * 68 + q * 16 + 4]  = d1;
    *(float4*)&deltaS[w * 68 + q * 16 + 8]  = d2;
    *(float4*)&deltaS[w * 68 + q * 16 + 12] = d3;
  }
  __syncthreads();

  // --- swap-out: wave-contiguous stores, 1KB/inst ---
  {
    const int s0 = tid & 15, hi = tid >> 4;   // float4 idx tid+256k -> w'=hi+16k, d'=s0*4
    const float4 r0 = *(const float4*)&deltaS[(hi +  0) * 68 + s0 * 4];
    const float4 r1 = *(const float4*)&deltaS[(hi + 16) * 68 + s0 * 4];
    const float4 r2 = *(const float4*)&deltaS[(hi + 32) * 68 + s0 * 4];
    const float4 r3 = *(const float4*)&deltaS[(hi + 48) * 68 + s0 * 4];
    float4* op = (float4*)(out + ((size_t)slice << 12));
    float4 o0 = xv0, o1 = xv1, o2 = xv2, o3 = xv3;
    o0.x += r0.x; o0.y += r0.y; o0.z += r0.z; o0.w += r0.w;
    o1.x += r1.x; o1.y += r1.y; o1.z += r1.z; o1.w += r1.w;
    o2.x += r2.x; o2.y += r2.y; o2.z += r2.z; o2.w += r2.w;
    o3.x += r3.x; o3.y += r3.y; o3.z += r3.z; o3.w += r3.w;
    op[tid]       = o0;
    op[tid + 256] = o1;
    op[tid + 512] = o2;
    op[tid + 768] = o3;
  }
}

} // namespace

extern "C" void kernel_launch(void* const* d_in, const int* in_sizes, int n_in,
                              void* d_out, int out_size, void* d_ws, size_t ws_size,
                              hipStream_t stream) {
  (void)in_sizes; (void)n_in; (void)out_size; (void)ws_size;
  const float* x  = (const float*)d_in[0];
  const float* w1 = (const float*)d_in[1];
  const float* b1 = (const float*)d_in[2];
  const float* w2 = (const float*)d_in[3];
  const float* b2 = (const float*)d_in[4];
  float* out = (float*)d_out;

  char* ws = (char*)d_ws;
  float2* buf1 = (float2*)ws;                          // 16384*576*8 = 75,497,472 B
  float2* buf2 = (float2*)(ws + 75497472);             // 256*2304*8  =  4,718,592 B
  float*  gm1  = (float*)(ws + 75497472 + 4718592);    // 4*2304*4    =     36,864 B

  hipLaunchKernelGGL(k1_fwd,   dim3(16384),    dim3(256), 0, stream, x, buf1);
  hipLaunchKernelGGL(k2_fwd,   dim3(9, 256),   dim3(256), 0, stream, buf1, buf2);
  hipLaunchKernelGGL(k3_gates, dim3(4),        dim3(256), 0, stream, buf2, w1, b1, w2, b2, gm1);
  hipLaunchKernelGGL(k4b_final,dim3(16384),    dim3(256), 0, stream, buf2, gm1, x, out);
}

// Round 9
// 250.873 us; speedup vs baseline: 2.3232x; 1.0208x over previous
//
#include <hip/hip_runtime.h>

namespace {

// cos(2*pi*n/64); sin(2*pi*n/64) = COS64[(n+48)&63]
constexpr float COS64[64] = {
  1.00000000f,  0.99518473f,  0.98078528f,  0.95694034f,
  0.92387953f,  0.88192126f,  0.83146961f,  0.77301045f,
  0.70710678f,  0.63439328f,  0.55557023f,  0.47139674f,
  0.38268343f,  0.29028468f,  0.19509032f,  0.09801714f,
  0.00000000f, -0.09801714f, -0.19509032f, -0.29028468f,
 -0.38268343f, -0.47139674f, -0.55557023f, -0.63439328f,
 -0.70710678f, -0.77301045f, -0.83146961f, -0.88192126f,
 -0.92387953f, -0.95694034f, -0.98078528f, -0.99518473f,
 -1.00000000f, -0.99518473f, -0.98078528f, -0.95694034f,
 -0.92387953f, -0.88192126f, -0.83146961f, -0.77301045f,
 -0.70710678f, -0.63439328f, -0.55557023f, -0.47139674f,
 -0.38268343f, -0.29028468f, -0.19509032f, -0.09801714f,
 -0.00000000f,  0.09801714f,  0.19509032f,  0.29028468f,
  0.38268343f,  0.47139674f,  0.55557023f,  0.63439328f,
  0.70710678f,  0.77301045f,  0.83146961f,  0.88192126f,
  0.92387953f,  0.95694034f,  0.98078528f,  0.99518473f };

constexpr float TWOPI_64 = 0.09817477042468103f; // 2*pi/64
constexpr int MM = 144;   // 16 ky * 9 kz
constexpr int GD = 2304;  // 16 kx * 144

// ---------------------------------------------------------------------------
// K1: fused z-DFT + w-DFT per slice. Coalesced x loads (1KB/inst) staged
// through padded LDS; z-DFT (compile-time twiddles + quad shuffle reduce)
// -> As[kz][w]; w-DFT (144 threads, 64-iter phase recurrence) ->
// buf1[slice][ky*9+kz] (144 complex = 1.15 KB/slice; buf1 total 18.9 MB).
// ---------------------------------------------------------------------------
__global__ __launch_bounds__(256) void k1_fwd(const float* __restrict__ x,
                                              float2* __restrict__ buf1) {
  __shared__ float xs[64 * 68];        // [w][68], pad 4
  __shared__ float2 As[9 * 67];        // A[kz][w], padded stride
  const int tid = threadIdx.x;
  const int slice = blockIdx.x;        // bc*64 + h
  const int w = tid >> 2, q = tid & 3;

  // wave-contiguous loads, transpose through LDS
  const float4* xp = (const float4*)(x + ((size_t)slice << 12));
  const float4 a0 = xp[tid];
  const float4 a1 = xp[tid + 256];
  const float4 a2 = xp[tid + 512];
  const float4 a3 = xp[tid + 768];
  {
    const int s0 = tid & 15, hi = tid >> 4;
    *(float4*)&xs[(hi +  0) * 68 + s0 * 4] = a0;
    *(float4*)&xs[(hi + 16) * 68 + s0 * 4] = a1;
    *(float4*)&xs[(hi + 32) * 68 + s0 * 4] = a2;
    *(float4*)&xs[(hi + 48) * 68 + s0 * 4] = a3;
  }
  __syncthreads();

  float xv[16];
  {
    const float4 b0 = *(const float4*)&xs[w * 68 + q * 16 + 0];
    const float4 b1 = *(const float4*)&xs[w * 68 + q * 16 + 4];
    const float4 b2 = *(const float4*)&xs[w * 68 + q * 16 + 8];
    const float4 b3 = *(const float4*)&xs[w * 68 + q * 16 + 12];
    xv[0]=b0.x; xv[1]=b0.y; xv[2]=b0.z; xv[3]=b0.w;
    xv[4]=b1.x; xv[5]=b1.y; xv[6]=b1.z; xv[7]=b1.w;
    xv[8]=b2.x; xv[9]=b2.y; xv[10]=b2.z; xv[11]=b2.w;
    xv[12]=b3.x; xv[13]=b3.y; xv[14]=b3.z; xv[15]=b3.w;
  }

  // z-DFT: sum_j xv[j] e^{-2pi i kz j/64}, compile-time twiddles
  float ar[9], ai[9];
#pragma unroll
  for (int kz = 0; kz < 9; ++kz) { ar[kz] = 0.f; ai[kz] = 0.f; }
#pragma unroll
  for (int j = 0; j < 16; ++j) {
    const float v = xv[j];
#pragma unroll
    for (int kz = 0; kz < 9; ++kz) {
      const int n = (kz * j) & 63;
      ar[kz] = fmaf(v, COS64[n], ar[kz]);
      ai[kz] = fmaf(v, -COS64[(n + 48) & 63], ai[kz]);
    }
  }
  // rotate by (-i)^{(q*kz)&3}, quad shuffle reduce, q==0 writes As
#pragma unroll
  for (int kz = 0; kz < 9; ++kz) {
    const int m = (q * kz) & 3;
    const float a = ar[kz], b = ai[kz];
    float r  = (m & 1) ? b : a;
    float i2 = (m & 1) ? a : b;
    r  = (m >= 2) ? -r : r;
    i2 = (m == 1 || m == 2) ? -i2 : i2;
    r  += __shfl_xor(r, 1);  r  += __shfl_xor(r, 2);
    i2 += __shfl_xor(i2, 1); i2 += __shfl_xor(i2, 2);
    if (q == 0) As[kz * 67 + w] = make_float2(r, i2);
  }
  __syncthreads();

  // w-DFT: B[ky][kz] = sum_w A[kz][w] e^{-2pi i ky w/64}  (phase recurrence)
  if (tid < MM) {
    const int ky = tid / 9, kz = tid - ky * 9;
    const float cs = COS64[ky], sn = COS64[(ky + 48) & 63];
    float px = 1.f, py = 0.f, br = 0.f, bi = 0.f;
    for (int ww = 0; ww < 64; ++ww) {
      const float2 a = As[kz * 67 + ww];
      br = fmaf(a.x, px, fmaf(-a.y, py, br));
      bi = fmaf(a.x, py, fmaf( a.y, px, bi));
      const float nx = fmaf(px, cs,  py * sn);
      const float ny = fmaf(py, cs, -px * sn);
      px = nx; py = ny;
    }
    buf1[(size_t)slice * MM + tid] = make_float2(br, bi);
  }
}

// ---------------------------------------------------------------------------
// K2: h-DFT only. Block = bc. Stage B[h][m] in 32-h chunks (36.9 KB LDS);
// thread (kx = tid>>4, g = tid&15) owns modes m = g*9..g*9+8, accumulates
// over 64 h with phase recurrence e^{-2pi i kx h/64}. Full 256-thread util.
// ---------------------------------------------------------------------------
__global__ __launch_bounds__(256) void k2_fwd(const float2* __restrict__ buf1,
                                              float2* __restrict__ buf2) {
  __shared__ float2 Bs[32 * MM];       // 36,864 B
  const int tid = threadIdx.x, bc = blockIdx.x;
  const int kx = tid >> 4, g = tid & 15;

  float accR[9], accI[9];
#pragma unroll
  for (int j = 0; j < 9; ++j) { accR[j] = 0.f; accI[j] = 0.f; }
  float qR = 1.f, qI = 0.f;            // e^{-2pi i kx h/64}
  const float hc = COS64[kx], hsn = COS64[(kx + 48) & 63];

  const float4* src = (const float4*)(buf1 + (size_t)bc * 64 * MM);
  for (int c2 = 0; c2 < 2; ++c2) {
    // stage 32 h-slices: 32*144 float2 = 2304 float4, 9 per thread
    float4* dst4 = (float4*)Bs;
    for (int i = tid; i < 2304; i += 256) dst4[i] = src[c2 * 2304 + i];
    __syncthreads();
    for (int hh = 0; hh < 32; ++hh) {
      const float2* row = Bs + hh * MM + g * 9;
#pragma unroll
      for (int j = 0; j < 9; ++j) {
        const float2 b = row[j];
        accR[j] = fmaf(b.x, qR, fmaf(-b.y, qI, accR[j]));
        accI[j] = fmaf(b.x, qI, fmaf( b.y, qR, accI[j]));
      }
      const float nR = fmaf(qR, hc, qI * hsn);
      const float nI = fmaf(qI, hc, -qR * hsn);
      qR = nR; qI = nI;
    }
    __syncthreads();
  }

  float2* dst = buf2 + (size_t)bc * GD + kx * MM + g * 9;
#pragma unroll
  for (int j = 0; j < 9; ++j) dst[j] = make_float2(accR[j], accI[j]);
}

// ---------------------------------------------------------------------------
// K3: gate MLP. pooled[b][c] = S_DC.re / 64^3. Writes g-1.
// ---------------------------------------------------------------------------
__global__ __launch_bounds__(256) void k3_gates(const float2* __restrict__ buf2,
    const float* __restrict__ w1, const float* __restrict__ b1,
    const float* __restrict__ w2, const float* __restrict__ b2,
    float* __restrict__ gm1) {
  __shared__ float pooled[64];
  __shared__ float hs[16];
  const int b = blockIdx.x, tid = threadIdx.x;
  if (tid < 64)
    pooled[tid] = buf2[(size_t)(b * 64 + tid) * GD].x * (1.f / 262144.f);
  __syncthreads();
  if (tid < 16) {
    float acc = b1[tid];
    for (int c = 0; c < 64; ++c) acc = fmaf(pooled[c], w1[c * 16 + tid], acc);
    hs[tid] = fmaxf(acc, 0.f);
  }
  __syncthreads();
#pragma unroll
  for (int r = 0; r < 9; ++r) {
    const int o = tid + r * 256;
    float acc = b2[o];
#pragma unroll
    for (int j = 0; j < 16; ++j) acc = fmaf(hs[j], w2[j * GD + o], acc);
    gm1[b * GD + o] = 1.f / (1.f + expf(-acc)) - 1.f;
  }
}

// ---------------------------------------------------------------------------
// K4b: inverse synthesis per slice (R8-verified). Phase 3 redistributes
// delta through padded LDS; wave-contiguous x loads and out stores.
// ---------------------------------------------------------------------------
__global__ __launch_bounds__(256) void k4b_final(const float2* __restrict__ S,
                                                 const float* __restrict__ gm1,
                                                 const float* __restrict__ x,
                                                 float* __restrict__ out) {
  __shared__ float2 C1s[MM];
  __shared__ float2 C2s[9 * 65];       // C2[kz][w], padded
  __shared__ float deltaS[64 * 68];    // [w][68], pad 4
  const int tid = threadIdx.x, slice = blockIdx.x;
  const int bc = slice >> 6, h = slice & 63, b = bc >> 6;
  const int w = tid >> 2, q = tid & 3;

  // prefetch x wave-contiguously: 1KB/inst
  const float4* xp = (const float4*)(x + ((size_t)slice << 12));
  const float4 xv0 = xp[tid];
  const float4 xv1 = xp[tid + 256];
  const float4 xv2 = xp[tid + 512];
  const float4 xv3 = xp[tid + 768];

  // --- phase 1: C1[m] = sum_kx (g-1)*S[bc][kx][m] e^{+2pi i kx h/64} ---
  if (tid < MM) {
    const float2* Sp = S + (size_t)bc * GD + tid;
    const float* Gp = gm1 + (size_t)b * GD + tid;
    float sn, cs;
    sincosf(TWOPI_64 * (float)h, &sn, &cs);   // step = e^{+2pi i h/64}
    float px = 1.f, py = 0.f, ar = 0.f, ai = 0.f;
#pragma unroll
    for (int kx = 0; kx < 16; ++kx) {
      const float2 sv = Sp[kx * MM];
      const float g = Gp[kx * MM];
      const float dR = sv.x * g, dI = sv.y * g;
      ar = fmaf(dR, px, fmaf(-dI, py, ar));
      ai = fmaf(dR, py, fmaf( dI, px, ai));
      const float nx = fmaf(px, cs, -py * sn);
      const float ny = fmaf(px, sn,  py * cs);
      px = nx; py = ny;
    }
    C1s[tid] = make_float2(ar, ai);
  }
  __syncthreads();

  // --- phase 2: C2[kz][w] = sum_ky C1[ky*9+kz] e^{+2pi i ky w/64} ---
  {
    float sn, cs;
    sincosf(TWOPI_64 * (float)w, &sn, &cs);   // step = e^{+2pi i w/64}
    const int kz0 = q, kz1 = q + 4;           // q==0 also does kz=8
    float a0r = 0.f, a0i = 0.f, a1r = 0.f, a1i = 0.f, a2r = 0.f, a2i = 0.f;
    float px = 1.f, py = 0.f;
    for (int ky = 0; ky < 16; ++ky) {
      const float2 c0 = C1s[ky * 9 + kz0];
      const float2 c1 = C1s[ky * 9 + kz1];
      a0r = fmaf(c0.x, px, fmaf(-c0.y, py, a0r));
      a0i = fmaf(c0.x, py, fmaf( c0.y, px, a0i));
      a1r = fmaf(c1.x, px, fmaf(-c1.y, py, a1r));
      a1i = fmaf(c1.x, py, fmaf( c1.y, px, a1i));
      if (q == 0) {
        const float2 c2v = C1s[ky * 9 + 8];
        a2r = fmaf(c2v.x, px, fmaf(-c2v.y, py, a2r));
        a2i = fmaf(c2v.x, py, fmaf( c2v.y, px, a2i));
      }
      const float nx = fmaf(px, cs, -py * sn);
      const float ny = fmaf(px, sn,  py * cs);
      px = nx; py = ny;
    }
    C2s[kz0 * 65 + w] = make_float2(a0r, a0i);
    C2s[kz1 * 65 + w] = make_float2(a1r, a1i);
    if (q == 0) C2s[8 * 65 + w] = make_float2(a2r, a2i);
  }
  __syncthreads();

  // --- phase 3: delta -> padded LDS ---
  {
    float cr[9], ci[9];
#pragma unroll
    for (int kz = 0; kz < 9; ++kz) {
      const float2 v = C2s[kz * 65 + w];
      const int m = (kz * q) & 3;                 // multiply by i^m
      const float a = v.x, b2_ = v.y;
      float r  = (m & 1) ? b2_ : a;
      float i2 = (m & 1) ? a : b2_;
      r  = (m == 1 || m == 2) ? -r : r;
      i2 = (m >= 2) ? -i2 : i2;
      cr[kz] = r; ci[kz] = i2;
    }
    float acc[16];
#pragma unroll
    for (int j = 0; j < 16; ++j) acc[j] = cr[0];
#pragma unroll
    for (int kz = 1; kz < 9; ++kz) {
#pragma unroll
      for (int j = 0; j < 16; ++j) {
        const int n = (kz * j) & 63;
        acc[j] = fmaf(cr[kz],  2.f * COS64[n], acc[j]);
        acc[j] = fmaf(ci[kz], -2.f * COS64[(n + 48) & 63], acc[j]);
      }
    }
    const float scale = 1.f / 262144.f;
    float4 d0, d1, d2, d3;
    d0.x = acc[0]  * scale; d0.y = acc[1]  * scale;
    d0.z = acc[2]  * scale; d0.w = acc[3]  * scale;
    d1.x = acc[4]  * scale; d1.y = acc[5]  * scale;
    d1.z = acc[6]  * scale; d1.w = acc[7]  * scale;
    d2.x = acc[8]  * scale; d2.y = acc[9]  * scale;
    d2.z = acc[10] * scale; d2.w = acc[11] * scale;
    d3.x = acc[12] * scale; d3.y = acc[13] * scale;
    d3.z = acc[14] * scale; d3.w = acc[15] * scale;
    *(float4*)&deltaS[w * 68 + q * 16 + 0]  = d0;
    *(float4*)&deltaS[w * 68 + q * 16 + 4]  = d1;
    *(float4*)&deltaS[w * 68 + q * 16 + 8]  = d2;
    *(float4*)&deltaS[w * 68 + q * 16 + 12] = d3;
  }
  __syncthreads();

  // --- swap-out: wave-contiguous stores, 1KB/inst ---
  {
    const int s0 = tid & 15, hi = tid >> 4;
    const float4 r0 = *(const float4*)&deltaS[(hi +  0) * 68 + s0 * 4];
    const float4 r1 = *(const float4*)&deltaS[(hi + 16) * 68 + s0 * 4];
    const float4 r2 = *(const float4*)&deltaS[(hi + 32) * 68 + s0 * 4];
    const float4 r3 = *(const float4*)&deltaS[(hi + 48) * 68 + s0 * 4];
    float4* op = (float4*)(out + ((size_t)slice << 12));
    float4 o0 = xv0, o1 = xv1, o2 = xv2, o3 = xv3;
    o0.x += r0.x; o0.y += r0.y; o0.z += r0.z; o0.w += r0.w;
    o1.x += r1.x; o1.y += r1.y; o1.z += r1.z; o1.w += r1.w;
    o2.x += r2.x; o2.y += r2.y; o2.z += r2.z; o2.w += r2.w;
    o3.x += r3.x; o3.y += r3.y; o3.z += r3.z; o3.w += r3.w;
    op[tid]       = o0;
    op[tid + 256] = o1;
    op[tid + 512] = o2;
    op[tid + 768] = o3;
  }
}

} // namespace

extern "C" void kernel_launch(void* const* d_in, const int* in_sizes, int n_in,
                              void* d_out, int out_size, void* d_ws, size_t ws_size,
                              hipStream_t stream) {
  (void)in_sizes; (void)n_in; (void)out_size; (void)ws_size;
  const float* x  = (const float*)d_in[0];
  const float* w1 = (const float*)d_in[1];
  const float* b1 = (const float*)d_in[2];
  const float* w2 = (const float*)d_in[3];
  const float* b2 = (const float*)d_in[4];
  float* out = (float*)d_out;

  char* ws = (char*)d_ws;
  float2* buf1 = (float2*)ws;                          // 16384*144*8 = 18,874,368 B
  float2* buf2 = (float2*)(ws + 18874368);             // 256*2304*8  =  4,718,592 B
  float*  gm1  = (float*)(ws + 18874368 + 4718592);    // 4*2304*4    =     36,864 B

  hipLaunchKernelGGL(k1_fwd,   dim3(16384),    dim3(256), 0, stream, x, buf1);
  hipLaunchKernelGGL(k2_fwd,   dim3(256),      dim3(256), 0, stream, buf1, buf2);
  hipLaunchKernelGGL(k3_gates, dim3(4),        dim3(256), 0, stream, buf2, w1, b1, w2, b2, gm1);
  hipLaunchKernelGGL(k4b_final,dim3(16384),    dim3(256), 0, stream, buf2, gm1, x, out);
}

// Round 10
// 237.702 us; speedup vs baseline: 2.4519x; 1.0554x over previous
//
#include <hip/hip_runtime.h>

namespace {

// cos(2*pi*n/64); sin(2*pi*n/64) = COS64[(n+48)&63]
constexpr float COS64[64] = {
  1.00000000f,  0.99518473f,  0.98078528f,  0.95694034f,
  0.92387953f,  0.88192126f,  0.83146961f,  0.77301045f,
  0.70710678f,  0.63439328f,  0.55557023f,  0.47139674f,
  0.38268343f,  0.29028468f,  0.19509032f,  0.09801714f,
  0.00000000f, -0.09801714f, -0.19509032f, -0.29028468f,
 -0.38268343f, -0.47139674f, -0.55557023f, -0.63439328f,
 -0.70710678f, -0.77301045f, -0.83146961f, -0.88192126f,
 -0.92387953f, -0.95694034f, -0.98078528f, -0.99518473f,
 -1.00000000f, -0.99518473f, -0.98078528f, -0.95694034f,
 -0.92387953f, -0.88192126f, -0.83146961f, -0.77301045f,
 -0.70710678f, -0.63439328f, -0.55557023f, -0.47139674f,
 -0.38268343f, -0.29028468f, -0.19509032f, -0.09801714f,
 -0.00000000f,  0.09801714f,  0.19509032f,  0.29028468f,
  0.38268343f,  0.47139674f,  0.55557023f,  0.63439328f,
  0.70710678f,  0.77301045f,  0.83146961f,  0.88192126f,
  0.92387953f,  0.95694034f,  0.98078528f,  0.99518473f };

constexpr float TWOPI_64 = 0.09817477042468103f; // 2*pi/64
constexpr int MM = 144;   // 16 ky * 9 kz
constexpr int GD = 2304;  // 16 kx * 144

// multiply (r,i) by (-i)^m, m in [0,4)
__device__ __forceinline__ void rot_mi(int m, float r_in, float i_in,
                                       float& r_out, float& i_out) {
  float r  = (m & 1) ? i_in : r_in;
  float i2 = (m & 1) ? r_in : i_in;
  r  = (m >= 2) ? -r : r;
  i2 = (m == 1 || m == 2) ? -i2 : i2;
  r_out = r; i_out = i2;
}

// ---------------------------------------------------------------------------
// K1: fused z-DFT + w-DFT per slice. Coalesced x loads (1KB/inst) staged
// through padded LDS; z-DFT (compile-time twiddles + quad shuffle reduce)
// -> As[kz][w]; w-DFT radix-4: w = 16a+b, inner a-sum via (-i)^{ky a}
// rotations, 16-step outer recurrence. buf1[slice][ky*9+kz].
// ---------------------------------------------------------------------------
__global__ __launch_bounds__(256) void k1_fwd(const float* __restrict__ x,
                                              float2* __restrict__ buf1) {
  __shared__ float xs[64 * 68];        // [w][68], pad 4
  __shared__ float2 As[9 * 67];        // A[kz][w], padded stride
  const int tid = threadIdx.x;
  const int slice = blockIdx.x;        // bc*64 + h
  const int w = tid >> 2, q = tid & 3;

  // wave-contiguous loads, transpose through LDS
  const float4* xp = (const float4*)(x + ((size_t)slice << 12));
  const float4 a0 = xp[tid];
  const float4 a1 = xp[tid + 256];
  const float4 a2 = xp[tid + 512];
  const float4 a3 = xp[tid + 768];
  {
    const int s0 = tid & 15, hi = tid >> 4;
    *(float4*)&xs[(hi +  0) * 68 + s0 * 4] = a0;
    *(float4*)&xs[(hi + 16) * 68 + s0 * 4] = a1;
    *(float4*)&xs[(hi + 32) * 68 + s0 * 4] = a2;
    *(float4*)&xs[(hi + 48) * 68 + s0 * 4] = a3;
  }
  __syncthreads();

  float xv[16];
  {
    const float4 b0 = *(const float4*)&xs[w * 68 + q * 16 + 0];
    const float4 b1 = *(const float4*)&xs[w * 68 + q * 16 + 4];
    const float4 b2 = *(const float4*)&xs[w * 68 + q * 16 + 8];
    const float4 b3 = *(const float4*)&xs[w * 68 + q * 16 + 12];
    xv[0]=b0.x; xv[1]=b0.y; xv[2]=b0.z; xv[3]=b0.w;
    xv[4]=b1.x; xv[5]=b1.y; xv[6]=b1.z; xv[7]=b1.w;
    xv[8]=b2.x; xv[9]=b2.y; xv[10]=b2.z; xv[11]=b2.w;
    xv[12]=b3.x; xv[13]=b3.y; xv[14]=b3.z; xv[15]=b3.w;
  }

  // z-DFT: sum_j xv[j] e^{-2pi i kz j/64}, compile-time twiddles
  float ar[9], ai[9];
#pragma unroll
  for (int kz = 0; kz < 9; ++kz) { ar[kz] = 0.f; ai[kz] = 0.f; }
#pragma unroll
  for (int j = 0; j < 16; ++j) {
    const float v = xv[j];
#pragma unroll
    for (int kz = 0; kz < 9; ++kz) {
      const int n = (kz * j) & 63;
      ar[kz] = fmaf(v, COS64[n], ar[kz]);
      ai[kz] = fmaf(v, -COS64[(n + 48) & 63], ai[kz]);
    }
  }
  // rotate by (-i)^{(q*kz)&3}, quad shuffle reduce, q==0 writes As
#pragma unroll
  for (int kz = 0; kz < 9; ++kz) {
    const int m = (q * kz) & 3;
    float r, i2;
    rot_mi(m, ar[kz], ai[kz], r, i2);
    r  += __shfl_xor(r, 1);  r  += __shfl_xor(r, 2);
    i2 += __shfl_xor(i2, 1); i2 += __shfl_xor(i2, 2);
    if (q == 0) As[kz * 67 + w] = make_float2(r, i2);
  }
  __syncthreads();

  // w-DFT radix-4: B[ky][kz] = sum_b e^{-2pi i ky b/64} *
  //                            sum_a A[kz][16a+b] (-i)^{(ky a)&3}
  if (tid < MM) {
    const int ky = tid / 9, kz = tid - ky * 9;
    const float cs = COS64[ky], sn = COS64[(ky + 48) & 63];
    const int m1 = ky & 3, m2 = (2 * ky) & 3, m3 = (3 * ky) & 3;
    float px = 1.f, py = 0.f, br = 0.f, bi = 0.f;
    const float2* Ak = As + kz * 67;
#pragma unroll
    for (int b = 0; b < 16; ++b) {
      const float2 v0 = Ak[b];
      const float2 v1 = Ak[b + 16];
      const float2 v2 = Ak[b + 32];
      const float2 v3 = Ak[b + 48];
      float gr = v0.x, gi = v0.y, rr, ri;
      rot_mi(m1, v1.x, v1.y, rr, ri); gr += rr; gi += ri;
      rot_mi(m2, v2.x, v2.y, rr, ri); gr += rr; gi += ri;
      rot_mi(m3, v3.x, v3.y, rr, ri); gr += rr; gi += ri;
      br = fmaf(gr, px, fmaf(-gi, py, br));
      bi = fmaf(gr, py, fmaf( gi, px, bi));
      const float nx = fmaf(px, cs,  py * sn);
      const float ny = fmaf(py, cs, -px * sn);
      px = nx; py = ny;
    }
    buf1[(size_t)slice * MM + tid] = make_float2(br, bi);
  }
}

// ---------------------------------------------------------------------------
// K2: h-DFT only. Block = bc. Stage B[h][m] in 32-h chunks (36.9 KB LDS);
// thread (kx = tid>>4, g = tid&15) owns modes m = g*9..g*9+8, accumulates
// over 64 h with phase recurrence e^{-2pi i kx h/64}. Full 256-thread util.
// ---------------------------------------------------------------------------
__global__ __launch_bounds__(256) void k2_fwd(const float2* __restrict__ buf1,
                                              float2* __restrict__ buf2) {
  __shared__ float2 Bs[32 * MM];       // 36,864 B
  const int tid = threadIdx.x, bc = blockIdx.x;
  const int kx = tid >> 4, g = tid & 15;

  float accR[9], accI[9];
#pragma unroll
  for (int j = 0; j < 9; ++j) { accR[j] = 0.f; accI[j] = 0.f; }
  float qR = 1.f, qI = 0.f;            // e^{-2pi i kx h/64}
  const float hc = COS64[kx], hsn = COS64[(kx + 48) & 63];

  const float4* src = (const float4*)(buf1 + (size_t)bc * 64 * MM);
  for (int c2 = 0; c2 < 2; ++c2) {
    float4* dst4 = (float4*)Bs;
    for (int i = tid; i < 2304; i += 256) dst4[i] = src[c2 * 2304 + i];
    __syncthreads();
    for (int hh = 0; hh < 32; ++hh) {
      const float2* row = Bs + hh * MM + g * 9;
#pragma unroll
      for (int j = 0; j < 9; ++j) {
        const float2 b = row[j];
        accR[j] = fmaf(b.x, qR, fmaf(-b.y, qI, accR[j]));
        accI[j] = fmaf(b.x, qI, fmaf( b.y, qR, accI[j]));
      }
      const float nR = fmaf(qR, hc, qI * hsn);
      const float nI = fmaf(qI, hc, -qR * hsn);
      qR = nR; qI = nI;
    }
    __syncthreads();
  }

  float2* dst = buf2 + (size_t)bc * GD + kx * MM + g * 9;
#pragma unroll
  for (int j = 0; j < 9; ++j) dst[j] = make_float2(accR[j], accI[j]);
}

// ---------------------------------------------------------------------------
// K3: gate MLP. pooled[b][c] = S_DC.re / 64^3. Writes g-1.
// ---------------------------------------------------------------------------
__global__ __launch_bounds__(256) void k3_gates(const float2* __restrict__ buf2,
    const float* __restrict__ w1, const float* __restrict__ b1,
    const float* __restrict__ w2, const float* __restrict__ b2,
    float* __restrict__ gm1) {
  __shared__ float pooled[64];
  __shared__ float hs[16];
  const int b = blockIdx.x, tid = threadIdx.x;
  if (tid < 64)
    pooled[tid] = buf2[(size_t)(b * 64 + tid) * GD].x * (1.f / 262144.f);
  __syncthreads();
  if (tid < 16) {
    float acc = b1[tid];
    for (int c = 0; c < 64; ++c) acc = fmaf(pooled[c], w1[c * 16 + tid], acc);
    hs[tid] = fmaxf(acc, 0.f);
  }
  __syncthreads();
#pragma unroll
  for (int r = 0; r < 9; ++r) {
    const int o = tid + r * 256;
    float acc = b2[o];
#pragma unroll
    for (int j = 0; j < 16; ++j) acc = fmaf(hs[j], w2[j * GD + o], acc);
    gm1[b * GD + o] = 1.f / (1.f + expf(-acc)) - 1.f;
  }
}

// ---------------------------------------------------------------------------
// K4b: inverse synthesis per slice (R8-verified structure). Slices processed
// in REVERSE so the x regions K1 read last (L3-hot) are consumed first.
// Phase 3 redistributes delta through padded LDS; wave-contiguous x loads
// and out stores.
// ---------------------------------------------------------------------------
__global__ __launch_bounds__(256) void k4b_final(const float2* __restrict__ S,
                                                 const float* __restrict__ gm1,
                                                 const float* __restrict__ x,
                                                 float* __restrict__ out) {
  __shared__ float2 C1s[MM];
  __shared__ float2 C2s[9 * 65];       // C2[kz][w], padded
  __shared__ float deltaS[64 * 68];    // [w][68], pad 4
  const int tid = threadIdx.x;
  const int slice = 16383 - blockIdx.x;     // reverse order for L3 x-hits
  const int bc = slice >> 6, h = slice & 63, b = bc >> 6;
  const int w = tid >> 2, q = tid & 3;

  // prefetch x wave-contiguously: 1KB/inst
  const float4* xp = (const float4*)(x + ((size_t)slice << 12));
  const float4 xv0 = xp[tid];
  const float4 xv1 = xp[tid + 256];
  const float4 xv2 = xp[tid + 512];
  const float4 xv3 = xp[tid + 768];

  // --- phase 1: C1[m] = sum_kx (g-1)*S[bc][kx][m] e^{+2pi i kx h/64} ---
  if (tid < MM) {
    const float2* Sp = S + (size_t)bc * GD + tid;
    const float* Gp = gm1 + (size_t)b * GD + tid;
    float sn, cs;
    sincosf(TWOPI_64 * (float)h, &sn, &cs);   // step = e^{+2pi i h/64}
    float px = 1.f, py = 0.f, ar = 0.f, ai = 0.f;
#pragma unroll
    for (int kx = 0; kx < 16; ++kx) {
      const float2 sv = Sp[kx * MM];
      const float g = Gp[kx * MM];
      const float dR = sv.x * g, dI = sv.y * g;
      ar = fmaf(dR, px, fmaf(-dI, py, ar));
      ai = fmaf(dR, py, fmaf( dI, px, ai));
      const float nx = fmaf(px, cs, -py * sn);
      const float ny = fmaf(px, sn,  py * cs);
      px = nx; py = ny;
    }
    C1s[tid] = make_float2(ar, ai);
  }
  __syncthreads();

  // --- phase 2: C2[kz][w] = sum_ky C1[ky*9+kz] e^{+2pi i ky w/64} ---
  {
    float sn, cs;
    sincosf(TWOPI_64 * (float)w, &sn, &cs);   // step = e^{+2pi i w/64}
    const int kz0 = q, kz1 = q + 4;           // q==0 also does kz=8
    float a0r = 0.f, a0i = 0.f, a1r = 0.f, a1i = 0.f, a2r = 0.f, a2i = 0.f;
    float px = 1.f, py = 0.f;
    for (int ky = 0; ky < 16; ++ky) {
      const float2 c0 = C1s[ky * 9 + kz0];
      const float2 c1 = C1s[ky * 9 + kz1];
      a0r = fmaf(c0.x, px, fmaf(-c0.y, py, a0r));
      a0i = fmaf(c0.x, py, fmaf( c0.y, px, a0i));
      a1r = fmaf(c1.x, px, fmaf(-c1.y, py, a1r));
      a1i = fmaf(c1.x, py, fmaf( c1.y, px, a1i));
      if (q == 0) {
        const float2 c2v = C1s[ky * 9 + 8];
        a2r = fmaf(c2v.x, px, fmaf(-c2v.y, py, a2r));
        a2i = fmaf(c2v.x, py, fmaf( c2v.y, px, a2i));
      }
      const float nx = fmaf(px, cs, -py * sn);
      const float ny = fmaf(px, sn,  py * cs);
      px = nx; py = ny;
    }
    C2s[kz0 * 65 + w] = make_float2(a0r, a0i);
    C2s[kz1 * 65 + w] = make_float2(a1r, a1i);
    if (q == 0) C2s[8 * 65 + w] = make_float2(a2r, a2i);
  }
  __syncthreads();

  // --- phase 3: delta -> padded LDS ---
  {
    float cr[9], ci[9];
#pragma unroll
    for (int kz = 0; kz < 9; ++kz) {
      const float2 v = C2s[kz * 65 + w];
      const int m = (kz * q) & 3;                 // multiply by i^m
      const float a = v.x, b2_ = v.y;
      float r  = (m & 1) ? b2_ : a;
      float i2 = (m & 1) ? a : b2_;
      r  = (m == 1 || m == 2) ? -r : r;
      i2 = (m >= 2) ? -i2 : i2;
      cr[kz] = r; ci[kz] = i2;
    }
    float acc[16];
#pragma unroll
    for (int j = 0; j < 16; ++j) acc[j] = cr[0];
#pragma unroll
    for (int kz = 1; kz < 9; ++kz) {
#pragma unroll
      for (int j = 0; j < 16; ++j) {
        const int n = (kz * j) & 63;
        acc[j] = fmaf(cr[kz],  2.f * COS64[n], acc[j]);
        acc[j] = fmaf(ci[kz], -2.f * COS64[(n + 48) & 63], acc[j]);
      }
    }
    const float scale = 1.f / 262144.f;
    float4 d0, d1, d2, d3;
    d0.x = acc[0]  * scale; d0.y = acc[1]  * scale;
    d0.z = acc[2]  * scale; d0.w = acc[3]  * scale;
    d1.x = acc[4]  * scale; d1.y = acc[5]  * scale;
    d1.z = acc[6]  * scale; d1.w = acc[7]  * scale;
    d2.x = acc[8]  * scale; d2.y = acc[9]  * scale;
    d2.z = acc[10] * scale; d2.w = acc[11] * scale;
    d3.x = acc[12] * scale; d3.y = acc[13] * scale;
    d3.z = acc[14] * scale; d3.w = acc[15] * scale;
    *(float4*)&deltaS[w * 68 + q * 16 + 0]  = d0;
    *(float4*)&deltaS[w * 68 + q * 16 + 4]  = d1;
    *(float4*)&deltaS[w * 68 + q * 16 + 8]  = d2;
    *(float4*)&deltaS[w * 68 + q * 16 + 12] = d3;
  }
  __syncthreads();

  // --- swap-out: wave-contiguous stores, 1KB/inst ---
  {
    const int s0 = tid & 15, hi = tid >> 4;
    const float4 r0 = *(const float4*)&deltaS[(hi +  0) * 68 + s0 * 4];
    const float4 r1 = *(const float4*)&deltaS[(hi + 16) * 68 + s0 * 4];
    const float4 r2 = *(const float4*)&deltaS[(hi + 32) * 68 + s0 * 4];
    const float4 r3 = *(const float4*)&deltaS[(hi + 48) * 68 + s0 * 4];
    float4* op = (float4*)(out + ((size_t)slice << 12));
    float4 o0 = xv0, o1 = xv1, o2 = xv2, o3 = xv3;
    o0.x += r0.x; o0.y += r0.y; o0.z += r0.z; o0.w += r0.w;
    o1.x += r1.x; o1.y += r1.y; o1.z += r1.z; o1.w += r1.w;
    o2.x += r2.x; o2.y += r2.y; o2.z += r2.z; o2.w += r2.w;
    o3.x += r3.x; o3.y += r3.y; o3.z += r3.z; o3.w += r3.w;
    op[tid]       = o0;
    op[tid + 256] = o1;
    op[tid + 512] = o2;
    op[tid + 768] = o3;
  }
}

} // namespace

extern "C" void kernel_launch(void* const* d_in, const int* in_sizes, int n_in,
                              void* d_out, int out_size, void* d_ws, size_t ws_size,
                              hipStream_t stream) {
  (void)in_sizes; (void)n_in; (void)out_size; (void)ws_size;
  const float* x  = (const float*)d_in[0];
  const float* w1 = (const float*)d_in[1];
  const float* b1 = (const float*)d_in[2];
  const float* w2 = (const float*)d_in[3];
  const float* b2 = (const float*)d_in[4];
  float* out = (float*)d_out;

  char* ws = (char*)d_ws;
  float2* buf1 = (float2*)ws;                          // 16384*144*8 = 18,874,368 B
  float2* buf2 = (float2*)(ws + 18874368);             // 256*2304*8  =  4,718,592 B
  float*  gm1  = (float*)(ws + 18874368 + 4718592);    // 4*2304*4    =     36,864 B

  hipLaunchKernelGGL(k1_fwd,   dim3(16384),    dim3(256), 0, stream, x, buf1);
  hipLaunchKernelGGL(k2_fwd,   dim3(256),      dim3(256), 0, stream, buf1, buf2);
  hipLaunchKernelGGL(k3_gates, dim3(4),        dim3(256), 0, stream, buf2, w1, b1, w2, b2, gm1);
  hipLaunchKernelGGL(k4b_final,dim3(16384),    dim3(256), 0, stream, buf2, gm1, x, out);
}

// Round 11
// 234.606 us; speedup vs baseline: 2.4843x; 1.0132x over previous
//
#include <hip/hip_runtime.h>

namespace {

// cos(2*pi*n/64); sin(2*pi*n/64) = COS64[(n+48)&63]
constexpr float COS64[64] = {
  1.00000000f,  0.99518473f,  0.98078528f,  0.95694034f,
  0.92387953f,  0.88192126f,  0.83146961f,  0.77301045f,
  0.70710678f,  0.63439328f,  0.55557023f,  0.47139674f,
  0.38268343f,  0.29028468f,  0.19509032f,  0.09801714f,
  0.00000000f, -0.09801714f, -0.19509032f, -0.29028468f,
 -0.38268343f, -0.47139674f, -0.55557023f, -0.63439328f,
 -0.70710678f, -0.77301045f, -0.83146961f, -0.88192126f,
 -0.92387953f, -0.95694034f, -0.98078528f, -0.99518473f,
 -1.00000000f, -0.99518473f, -0.98078528f, -0.95694034f,
 -0.92387953f, -0.88192126f, -0.83146961f, -0.77301045f,
 -0.70710678f, -0.63439328f, -0.55557023f, -0.47139674f,
 -0.38268343f, -0.29028468f, -0.19509032f, -0.09801714f,
 -0.00000000f,  0.09801714f,  0.19509032f,  0.29028468f,
  0.38268343f,  0.47139674f,  0.55557023f,  0.63439328f,
  0.70710678f,  0.77301045f,  0.83146961f,  0.88192126f,
  0.92387953f,  0.95694034f,  0.98078528f,  0.99518473f };

constexpr float TWOPI_64 = 0.09817477042468103f; // 2*pi/64
constexpr int MM = 144;   // 16 ky * 9 kz
constexpr int GD = 2304;  // 16 kx * 144

// multiply (r,i) by (-i)^m, m in [0,4)
__device__ __forceinline__ void rot_mi(int m, float r_in, float i_in,
                                       float& r_out, float& i_out) {
  float r  = (m & 1) ? i_in : r_in;
  float i2 = (m & 1) ? r_in : i_in;
  r  = (m >= 2) ? -r : r;
  i2 = (m == 1 || m == 2) ? -i2 : i2;
  r_out = r; i_out = i2;
}

// ---------------------------------------------------------------------------
// K1: fused z-DFT + w-DFT per slice (R10-verified).
// ---------------------------------------------------------------------------
__global__ __launch_bounds__(256) void k1_fwd(const float* __restrict__ x,
                                              float2* __restrict__ buf1) {
  __shared__ float xs[64 * 68];        // [w][68], pad 4
  __shared__ float2 As[9 * 67];        // A[kz][w], padded stride
  const int tid = threadIdx.x;
  const int slice = blockIdx.x;        // bc*64 + h
  const int w = tid >> 2, q = tid & 3;

  const float4* xp = (const float4*)(x + ((size_t)slice << 12));
  const float4 a0 = xp[tid];
  const float4 a1 = xp[tid + 256];
  const float4 a2 = xp[tid + 512];
  const float4 a3 = xp[tid + 768];
  {
    const int s0 = tid & 15, hi = tid >> 4;
    *(float4*)&xs[(hi +  0) * 68 + s0 * 4] = a0;
    *(float4*)&xs[(hi + 16) * 68 + s0 * 4] = a1;
    *(float4*)&xs[(hi + 32) * 68 + s0 * 4] = a2;
    *(float4*)&xs[(hi + 48) * 68 + s0 * 4] = a3;
  }
  __syncthreads();

  float xv[16];
  {
    const float4 b0 = *(const float4*)&xs[w * 68 + q * 16 + 0];
    const float4 b1 = *(const float4*)&xs[w * 68 + q * 16 + 4];
    const float4 b2 = *(const float4*)&xs[w * 68 + q * 16 + 8];
    const float4 b3 = *(const float4*)&xs[w * 68 + q * 16 + 12];
    xv[0]=b0.x; xv[1]=b0.y; xv[2]=b0.z; xv[3]=b0.w;
    xv[4]=b1.x; xv[5]=b1.y; xv[6]=b1.z; xv[7]=b1.w;
    xv[8]=b2.x; xv[9]=b2.y; xv[10]=b2.z; xv[11]=b2.w;
    xv[12]=b3.x; xv[13]=b3.y; xv[14]=b3.z; xv[15]=b3.w;
  }

  float ar[9], ai[9];
#pragma unroll
  for (int kz = 0; kz < 9; ++kz) { ar[kz] = 0.f; ai[kz] = 0.f; }
#pragma unroll
  for (int j = 0; j < 16; ++j) {
    const float v = xv[j];
#pragma unroll
    for (int kz = 0; kz < 9; ++kz) {
      const int n = (kz * j) & 63;
      ar[kz] = fmaf(v, COS64[n], ar[kz]);
      ai[kz] = fmaf(v, -COS64[(n + 48) & 63], ai[kz]);
    }
  }
#pragma unroll
  for (int kz = 0; kz < 9; ++kz) {
    const int m = (q * kz) & 3;
    float r, i2;
    rot_mi(m, ar[kz], ai[kz], r, i2);
    r  += __shfl_xor(r, 1);  r  += __shfl_xor(r, 2);
    i2 += __shfl_xor(i2, 1); i2 += __shfl_xor(i2, 2);
    if (q == 0) As[kz * 67 + w] = make_float2(r, i2);
  }
  __syncthreads();

  // w-DFT radix-4
  if (tid < MM) {
    const int ky = tid / 9, kz = tid - ky * 9;
    const float cs = COS64[ky], sn = COS64[(ky + 48) & 63];
    const int m1 = ky & 3, m2 = (2 * ky) & 3, m3 = (3 * ky) & 3;
    float px = 1.f, py = 0.f, br = 0.f, bi = 0.f;
    const float2* Ak = As + kz * 67;
#pragma unroll
    for (int b = 0; b < 16; ++b) {
      const float2 v0 = Ak[b];
      const float2 v1 = Ak[b + 16];
      const float2 v2 = Ak[b + 32];
      const float2 v3 = Ak[b + 48];
      float gr = v0.x, gi = v0.y, rr, ri;
      rot_mi(m1, v1.x, v1.y, rr, ri); gr += rr; gi += ri;
      rot_mi(m2, v2.x, v2.y, rr, ri); gr += rr; gi += ri;
      rot_mi(m3, v3.x, v3.y, rr, ri); gr += rr; gi += ri;
      br = fmaf(gr, px, fmaf(-gi, py, br));
      bi = fmaf(gr, py, fmaf( gi, px, bi));
      const float nx = fmaf(px, cs,  py * sn);
      const float ny = fmaf(py, cs, -px * sn);
      px = nx; py = ny;
    }
    buf1[(size_t)slice * MM + tid] = make_float2(br, bi);
  }
}

// ---------------------------------------------------------------------------
// K2: h-DFT (R9-verified). Block = bc; (kx,g) ownership, 32-h LDS chunks.
// ---------------------------------------------------------------------------
__global__ __launch_bounds__(256) void k2_fwd(const float2* __restrict__ buf1,
                                              float2* __restrict__ buf2) {
  __shared__ float2 Bs[32 * MM];       // 36,864 B
  const int tid = threadIdx.x, bc = blockIdx.x;
  const int kx = tid >> 4, g = tid & 15;

  float accR[9], accI[9];
#pragma unroll
  for (int j = 0; j < 9; ++j) { accR[j] = 0.f; accI[j] = 0.f; }
  float qR = 1.f, qI = 0.f;            // e^{-2pi i kx h/64}
  const float hc = COS64[kx], hsn = COS64[(kx + 48) & 63];

  const float4* src = (const float4*)(buf1 + (size_t)bc * 64 * MM);
  for (int c2 = 0; c2 < 2; ++c2) {
    float4* dst4 = (float4*)Bs;
    for (int i = tid; i < 2304; i += 256) dst4[i] = src[c2 * 2304 + i];
    __syncthreads();
    for (int hh = 0; hh < 32; ++hh) {
      const float2* row = Bs + hh * MM + g * 9;
#pragma unroll
      for (int j = 0; j < 9; ++j) {
        const float2 b = row[j];
        accR[j] = fmaf(b.x, qR, fmaf(-b.y, qI, accR[j]));
        accI[j] = fmaf(b.x, qI, fmaf( b.y, qR, accI[j]));
      }
      const float nR = fmaf(qR, hc, qI * hsn);
      const float nI = fmaf(qI, hc, -qR * hsn);
      qR = nR; qI = nI;
    }
    __syncthreads();
  }

  float2* dst = buf2 + (size_t)bc * GD + kx * MM + g * 9;
#pragma unroll
  for (int j = 0; j < 9; ++j) dst[j] = make_float2(accR[j], accI[j]);
}

// ---------------------------------------------------------------------------
// K3: gate MLP (verified). Writes g-1.
// ---------------------------------------------------------------------------
__global__ __launch_bounds__(256) void k3_gates(const float2* __restrict__ buf2,
    const float* __restrict__ w1, const float* __restrict__ b1,
    const float* __restrict__ w2, const float* __restrict__ b2,
    float* __restrict__ gm1) {
  __shared__ float pooled[64];
  __shared__ float hs[16];
  const int b = blockIdx.x, tid = threadIdx.x;
  if (tid < 64)
    pooled[tid] = buf2[(size_t)(b * 64 + tid) * GD].x * (1.f / 262144.f);
  __syncthreads();
  if (tid < 16) {
    float acc = b1[tid];
    for (int c = 0; c < 64; ++c) acc = fmaf(pooled[c], w1[c * 16 + tid], acc);
    hs[tid] = fmaxf(acc, 0.f);
  }
  __syncthreads();
#pragma unroll
  for (int r = 0; r < 9; ++r) {
    const int o = tid + r * 256;
    float acc = b2[o];
#pragma unroll
    for (int j = 0; j < 16; ++j) acc = fmaf(hs[j], w2[j * GD + o], acc);
    gm1[b * GD + o] = 1.f / (1.f + expf(-acc)) - 1.f;
  }
}

// ---------------------------------------------------------------------------
// K4a: hoisted k4b phase 1. Block = bc. Stage D=(g-1)*S in LDS once,
// rotation table rot[h][kx] from COS64; all 256 threads (h, mq) compute
// C1[bc,h,m] = sum_kx D[kx][m] e^{+2pi i kx h/64}, m = mq*36..+35.
// ---------------------------------------------------------------------------
__global__ __launch_bounds__(256) void k4a_c1(const float2* __restrict__ S,
                                              const float* __restrict__ gm1,
                                              float2* __restrict__ C1buf) {
  __shared__ float2 Dg[GD];            // 18,432 B
  __shared__ float2 rotS[64 * 16];     //  8,192 B
  const int tid = threadIdx.x, bc = blockIdx.x, b = bc >> 6;

  for (int i = tid; i < GD; i += 256) {
    const float2 sv = S[(size_t)bc * GD + i];
    const float g = gm1[(size_t)b * GD + i];
    Dg[i] = make_float2(sv.x * g, sv.y * g);
  }
#pragma unroll
  for (int u = 0; u < 4; ++u) {
    const int e = tid * 4 + u, hh = e >> 4, kx = e & 15;
    const int n = (kx * hh) & 63;
    rotS[e] = make_float2(COS64[n], COS64[(n + 48) & 63]);
  }
  __syncthreads();

  const int h = tid >> 2, mq = tid & 3;
  float2* dst = C1buf + ((size_t)(bc * 64 + h)) * MM + mq * 36;
  for (int jb = 0; jb < 3; ++jb) {
    float aR[12], aI[12];
#pragma unroll
    for (int j = 0; j < 12; ++j) { aR[j] = 0.f; aI[j] = 0.f; }
    for (int kx = 0; kx < 16; ++kx) {
      const float2 rot = rotS[h * 16 + kx];
      const float2* drow = Dg + kx * MM + mq * 36 + jb * 12;
#pragma unroll
      for (int j = 0; j < 12; ++j) {
        const float2 d = drow[j];
        aR[j] = fmaf(d.x, rot.x, fmaf(-d.y, rot.y, aR[j]));
        aI[j] = fmaf(d.x, rot.y, fmaf( d.y, rot.x, aI[j]));
      }
    }
#pragma unroll
    for (int j = 0; j < 12; ++j) dst[jb * 12 + j] = make_float2(aR[j], aI[j]);
  }
}

// ---------------------------------------------------------------------------
// K4b: inverse synthesis per slice. Phase 1 replaced by one coalesced C1-row
// load. Reverse slice order for L3 x-hits; LDS redistribution; wave-
// contiguous x loads and out stores (all R8/R10-verified).
// ---------------------------------------------------------------------------
__global__ __launch_bounds__(256) void k4b_final(const float2* __restrict__ C1buf,
                                                 const float* __restrict__ x,
                                                 float* __restrict__ out) {
  __shared__ float2 C1s[MM];
  __shared__ float2 C2s[9 * 65];       // C2[kz][w], padded
  __shared__ float deltaS[64 * 68];    // [w][68], pad 4
  const int tid = threadIdx.x;
  const int slice = 16383 - blockIdx.x;     // reverse order for L3 x-hits
  const int w = tid >> 2, q = tid & 3;

  // prefetch x wave-contiguously: 1KB/inst
  const float4* xp = (const float4*)(x + ((size_t)slice << 12));
  const float4 xv0 = xp[tid];
  const float4 xv1 = xp[tid + 256];
  const float4 xv2 = xp[tid + 512];
  const float4 xv3 = xp[tid + 768];

  // --- phase 1 (now a load): C1 row, 144 float2 = 72 float4, coalesced ---
  if (tid < 72) {
    const float4* cp = (const float4*)(C1buf + (size_t)slice * MM);
    ((float4*)C1s)[tid] = cp[tid];
  }
  __syncthreads();

  // --- phase 2: C2[kz][w] = sum_ky C1[ky*9+kz] e^{+2pi i ky w/64} ---
  {
    float sn, cs;
    sincosf(TWOPI_64 * (float)w, &sn, &cs);   // step = e^{+2pi i w/64}
    const int kz0 = q, kz1 = q + 4;           // q==0 also does kz=8
    float a0r = 0.f, a0i = 0.f, a1r = 0.f, a1i = 0.f, a2r = 0.f, a2i = 0.f;
    float px = 1.f, py = 0.f;
    for (int ky = 0; ky < 16; ++ky) {
      const float2 c0 = C1s[ky * 9 + kz0];
      const float2 c1 = C1s[ky * 9 + kz1];
      a0r = fmaf(c0.x, px, fmaf(-c0.y, py, a0r));
      a0i = fmaf(c0.x, py, fmaf( c0.y, px, a0i));
      a1r = fmaf(c1.x, px, fmaf(-c1.y, py, a1r));
      a1i = fmaf(c1.x, py, fmaf( c1.y, px, a1i));
      if (q == 0) {
        const float2 c2v = C1s[ky * 9 + 8];
        a2r = fmaf(c2v.x, px, fmaf(-c2v.y, py, a2r));
        a2i = fmaf(c2v.x, py, fmaf( c2v.y, px, a2i));
      }
      const float nx = fmaf(px, cs, -py * sn);
      const float ny = fmaf(px, sn,  py * cs);
      px = nx; py = ny;
    }
    C2s[kz0 * 65 + w] = make_float2(a0r, a0i);
    C2s[kz1 * 65 + w] = make_float2(a1r, a1i);
    if (q == 0) C2s[8 * 65 + w] = make_float2(a2r, a2i);
  }
  __syncthreads();

  // --- phase 3: delta -> padded LDS ---
  {
    float cr[9], ci[9];
#pragma unroll
    for (int kz = 0; kz < 9; ++kz) {
      const float2 v = C2s[kz * 65 + w];
      const int m = (kz * q) & 3;                 // multiply by i^m
      const float a = v.x, b2_ = v.y;
      float r  = (m & 1) ? b2_ : a;
      float i2 = (m & 1) ? a : b2_;
      r  = (m == 1 || m == 2) ? -r : r;
      i2 = (m >= 2) ? -i2 : i2;
      cr[kz] = r; ci[kz] = i2;
    }
    float acc[16];
#pragma unroll
    for (int j = 0; j < 16; ++j) acc[j] = cr[0];
#pragma unroll
    for (int kz = 1; kz < 9; ++kz) {
#pragma unroll
      for (int j = 0; j < 16; ++j) {
        const int n = (kz * j) & 63;
        acc[j] = fmaf(cr[kz],  2.f * COS64[n], acc[j]);
        acc[j] = fmaf(ci[kz], -2.f * COS64[(n + 48) & 63], acc[j]);
      }
    }
    const float scale = 1.f / 262144.f;
    float4 d0, d1, d2, d3;
    d0.x = acc[0]  * scale; d0.y = acc[1]  * scale;
    d0.z = acc[2]  * scale; d0.w = acc[3]  * scale;
    d1.x = acc[4]  * scale; d1.y = acc[5]  * scale;
    d1.z = acc[6]  * scale; d1.w = acc[7]  * scale;
    d2.x = acc[8]  * scale; d2.y = acc[9]  * scale;
    d2.z = acc[10] * scale; d2.w = acc[11] * scale;
    d3.x = acc[12] * scale; d3.y = acc[13] * scale;
    d3.z = acc[14] * scale; d3.w = acc[15] * scale;
    *(float4*)&deltaS[w * 68 + q * 16 + 0]  = d0;
    *(float4*)&deltaS[w * 68 + q * 16 + 4]  = d1;
    *(float4*)&deltaS[w * 68 + q * 16 + 8]  = d2;
    *(float4*)&deltaS[w * 68 + q * 16 + 12] = d3;
  }
  __syncthreads();

  // --- swap-out: wave-contiguous stores, 1KB/inst ---
  {
    const int s0 = tid & 15, hi = tid >> 4;
    const float4 r0 = *(const float4*)&deltaS[(hi +  0) * 68 + s0 * 4];
    const float4 r1 = *(const float4*)&deltaS[(hi + 16) * 68 + s0 * 4];
    const float4 r2 = *(const float4*)&deltaS[(hi + 32) * 68 + s0 * 4];
    const float4 r3 = *(const float4*)&deltaS[(hi + 48) * 68 + s0 * 4];
    float4* op = (float4*)(out + ((size_t)slice << 12));
    float4 o0 = xv0, o1 = xv1, o2 = xv2, o3 = xv3;
    o0.x += r0.x; o0.y += r0.y; o0.z += r0.z; o0.w += r0.w;
    o1.x += r1.x; o1.y += r1.y; o1.z += r1.z; o1.w += r1.w;
    o2.x += r2.x; o2.y += r2.y; o2.z += r2.z; o2.w += r2.w;
    o3.x += r3.x; o3.y += r3.y; o3.z += r3.z; o3.w += r3.w;
    op[tid]       = o0;
    op[tid + 256] = o1;
    op[tid + 512] = o2;
    op[tid + 768] = o3;
  }
}

} // namespace

extern "C" void kernel_launch(void* const* d_in, const int* in_sizes, int n_in,
                              void* d_out, int out_size, void* d_ws, size_t ws_size,
                              hipStream_t stream) {
  (void)in_sizes; (void)n_in; (void)out_size; (void)ws_size;
  const float* x  = (const float*)d_in[0];
  const float* w1 = (const float*)d_in[1];
  const float* b1 = (const float*)d_in[2];
  const float* w2 = (const float*)d_in[3];
  const float* b2 = (const float*)d_in[4];
  float* out = (float*)d_out;

  char* ws = (char*)d_ws;
  float2* buf1  = (float2*)ws;                         // 16384*144*8 = 18,874,368 B
  float2* buf2  = (float2*)(ws + 18874368);            // 256*2304*8  =  4,718,592 B
  float*  gm1   = (float*)(ws + 23592960);             // 4*2304*4    =     36,864 B
  float2* c1buf = (float2*)(ws + 23629824);            // 16384*144*8 = 18,874,368 B

  hipLaunchKernelGGL(k1_fwd,   dim3(16384),    dim3(256), 0, stream, x, buf1);
  hipLaunchKernelGGL(k2_fwd,   dim3(256),      dim3(256), 0, stream, buf1, buf2);
  hipLaunchKernelGGL(k3_gates, dim3(4),        dim3(256), 0, stream, buf2, w1, b1, w2, b2, gm1);
  hipLaunchKernelGGL(k4a_c1,   dim3(256),      dim3(256), 0, stream, buf2, gm1, c1buf);
  hipLaunchKernelGGL(k4b_final,dim3(16384),    dim3(256), 0, stream, c1buf, x, out);
}